// Round 2
// baseline (399.308 us; speedup 1.0000x reference)
//
#include <hip/hip_runtime.h>
#include <stdint.h>

typedef unsigned short u16;
typedef unsigned int u32;
typedef unsigned long long u64;
typedef __attribute__((ext_vector_type(8))) short short8;
typedef __attribute__((ext_vector_type(4))) float f32x4;

#define MFMA16(a,b,c) __builtin_amdgcn_mfma_f32_16x16x32_bf16((a),(b),(c),0,0,0)

__device__ __forceinline__ u16 f2bf(float f){
  u32 u = __builtin_bit_cast(u32, f);
  u32 r = u + 0x7FFFu + ((u >> 16) & 1u);
  return (u16)(r >> 16);
}

__device__ __forceinline__ void gload16(const void* g, void* l){
  __builtin_amdgcn_global_load_lds((__attribute__((address_space(1))) void*)(uintptr_t)g,
                                   (__attribute__((address_space(3))) void*)l, 16, 0, 0);
}

// ---------------- prep: cast x + weights to bf16 ----------------
__global__ __launch_bounds__(256) void k_prep(const float* __restrict__ x,
    const float* __restrict__ wq, const float* __restrict__ wk,
    const float* __restrict__ wv, const float* __restrict__ wo,
    u16* __restrict__ xb, u16* __restrict__ wqb, u16* __restrict__ wkb,
    u16* __restrict__ wvb, u16* __restrict__ wob){
  for (int j = blockIdx.x*blockDim.x + threadIdx.x; j < 2097152; j += gridDim.x*blockDim.x){
    const float* src; u16* dst; int off;
    if (j < 1048576){ src = x; dst = xb; off = j; }
    else {
      int r = (j - 1048576) >> 18; off = (j - 1048576) & 262143;
      src = (r==0)?wq:(r==1)?wk:(r==2)?wv:wo;
      dst = (r==0)?wqb:(r==1)?wkb:(r==2)?wvb:wob;
    }
    float4 v = ((const float4*)src)[off];
    ushort4 o;
    o.x = f2bf(v.x); o.y = f2bf(v.y); o.z = f2bf(v.z); o.w = f2bf(v.w);
    ((ushort4*)dst)[off] = o;
  }
}

// ---------------- pos_bias[b,h,s] = dot(pos_emb[b,s,:], w_pos[h,:]) ----------------
__global__ __launch_bounds__(256) void k_posb(const float* __restrict__ pos,
    const float* __restrict__ wpos, float* __restrict__ posb){
  int row = blockIdx.x*4 + (threadIdx.x >> 6);   // (b*2048+s), 4096 rows
  int lane = threadIdx.x & 63;
  const float* pr = pos + (size_t)row*1024;
  float pv[16];
  #pragma unroll
  for (int t=0;t<4;t++){
    float4 v = ((const float4*)pr)[lane + 64*t];
    pv[4*t+0]=v.x; pv[4*t+1]=v.y; pv[4*t+2]=v.z; pv[4*t+3]=v.w;
  }
  int b = row >> 11, s = row & 2047;
  for (int h=0; h<16; h++){
    const float* wr = wpos + h*1024;
    float acc = 0.f;
    #pragma unroll
    for (int t=0;t<4;t++){
      float4 w = ((const float4*)wr)[lane + 64*t];
      acc += pv[4*t+0]*w.x + pv[4*t+1]*w.y + pv[4*t+2]*w.z + pv[4*t+3]*w.w;
    }
    #pragma unroll
    for (int m=1;m<64;m<<=1) acc += __shfl_xor(acc, m);
    if (lane == 0) posb[(b*16 + h)*2048 + s] = acc;
  }
}

// ---------------- pack mask to bits ----------------
__global__ __launch_bounds__(256) void k_mask(const int* __restrict__ mask, u64* __restrict__ pm){
  int wi = (blockIdx.x*blockDim.x + threadIdx.x) >> 6;
  int lane = threadIdx.x & 63;
  int nw = (gridDim.x*blockDim.x) >> 6;
  for (int w = wi; w < 131072; w += nw){
    int v = mask[(size_t)w*64 + lane];
    u64 bits = __ballot(v != 0);
    if (lane == 0) pm[w] = bits;
  }
}

// ---------------- fused QKV projection GEMM (m97 structure) ----------------
// C = Xb(4096x1024) * W^T, W in {wq,wk,wv}; writes (b,h,s,d) bf16
__global__ __launch_bounds__(256) void k_qkv(const u16* __restrict__ xb,
    const u16* __restrict__ wqb, const u16* __restrict__ wkb, const u16* __restrict__ wvb,
    const float* __restrict__ bq, const float* __restrict__ bk, const float* __restrict__ bv,
    u16* __restrict__ Q, u16* __restrict__ K, u16* __restrict__ V){
  __shared__ __align__(16) u16 As[128*32];
  __shared__ __align__(16) u16 Bs[128*32];
  const int bx = blockIdx.x, by = blockIdx.y;
  const int tid = threadIdx.x, wid = tid >> 6, lane = tid & 63;
  const int wsel = by >> 3;
  const u16* W = (wsel==0) ? wqb : (wsel==1 ? wkb : wvb);
  const float* bias = (wsel==0) ? bq : (wsel==1 ? bk : bv);
  u16* dst = (wsel==0) ? Q : (wsel==1 ? K : V);
  const int m0 = bx*128, n0 = (by & 7)*128;
  const int wm = wid >> 1, wn = wid & 1;
  const int g8 = (lane >> 4)*8;

  f32x4 acc[4][4];
  f32x4 z4 = {0.f,0.f,0.f,0.f};
  #pragma unroll
  for (int mf=0;mf<4;mf++)
    #pragma unroll
    for (int nf=0;nf<4;nf++) acc[mf][nf] = z4;

  for (int kt=0; kt<32; kt++){
    #pragma unroll
    for (int jj=0;jj<2;jj++){
      int sp = wid*2 + jj;
      int p = sp*64 + lane;
      int row = p >> 2, c4 = p & 3;
      gload16(xb + (size_t)(m0+row)*1024 + kt*32 + c4*8, &As[sp*512]);
      gload16(W  + (size_t)(n0+row)*1024 + kt*32 + c4*8, &Bs[sp*512]);
    }
    __syncthreads();
    short8 a[4], b[4];
    #pragma unroll
    for (int mf=0;mf<4;mf++) a[mf] = *(const short8*)&As[(wm*64 + mf*16 + (lane&15))*32 + g8];
    #pragma unroll
    for (int nf=0;nf<4;nf++) b[nf] = *(const short8*)&Bs[(wn*64 + nf*16 + (lane&15))*32 + g8];
    #pragma unroll
    for (int mf=0;mf<4;mf++)
      #pragma unroll
      for (int nf=0;nf<4;nf++) acc[mf][nf] = MFMA16(a[mf], b[nf], acc[mf][nf]);
    __syncthreads();
  }

  #pragma unroll
  for (int nf=0;nf<4;nf++){
    int nloc = n0 + wn*64 + nf*16 + (lane & 15);   // 0..1023 within this weight
    float bb = bias[nloc];
    int h = nloc >> 6, d = nloc & 63;
    #pragma unroll
    for (int mf=0;mf<4;mf++)
      #pragma unroll
      for (int i=0;i<4;i++){
        int m = m0 + wm*64 + mf*16 + (lane>>4)*4 + i;
        int bt = m >> 11, s = m & 2047;
        dst[((size_t)((bt*16 + h)*2048 + s))*64 + d] = f2bf(acc[mf][nf][i] + bb);
      }
  }
}

// ---------------- flash attention ----------------
// Per block: one (b,h), 64 queries (4 waves x 16). KV tile = 64.
// K in LDS XOR-swizzled (linear dest via pre-swizzled global src).
// V reg-staged TRANSPOSED into LDS as Vt[d][key], same XOR swizzle family.
__global__ __launch_bounds__(256) void k_attn(const u16* __restrict__ Qg, const u16* __restrict__ Kg,
    const u16* __restrict__ Vg, const float* __restrict__ posb, const u64* __restrict__ pmask,
    u16* __restrict__ AO){
  __shared__ __align__(16) u16 Ks[64*64];
  __shared__ __align__(16) u16 Vts[64*64];
  __shared__ __align__(16) u16 Ps[4*16*64];
  const int bid = blockIdx.x;
  const int bh = bid >> 5;       // 0..31, consecutive blocks share K/V for L2
  const int qt = bid & 31;
  const int b_ = bh >> 4;
  const int h_ = bh & 15;
  const int tid = threadIdx.x, wid = tid >> 6, lane = tid & 63;
  const int g = lane >> 4, c = lane & 15;
  const int q0w = qt*64 + wid*16;

  short8 qf0, qf1;
  {
    const u16* qp = Qg + ((size_t)(bh*2048 + q0w + c))*64 + g*8;
    qf0 = *(const short8*)qp;
    qf1 = *(const short8*)(qp + 32);
  }
  f32x4 Oa[4];
  f32x4 z4 = {0.f,0.f,0.f,0.f};
  #pragma unroll
  for (int i=0;i<4;i++) Oa[i] = z4;
  float mi[4], li[4];
  #pragma unroll
  for (int i=0;i<4;i++){ mi[i] = -1e30f; li[i] = 0.f; }

  u16* Pw = Ps + wid*1024;

  for (int kt=0; kt<32; kt++){
    // ---- stage K via global_load_lds (waves 0,1), pre-swizzled source ----
    if (wid < 2){
      #pragma unroll
      for (int jj=0;jj<4;jj++){
        int sx = wid*4 + jj;
        int p = sx*64 + lane;
        int key = p >> 3, o16 = p & 7;
        gload16(Kg + ((size_t)(bh*2048 + kt*64 + key))*64 + (o16 ^ (key&7))*8, &Ks[sx*512]);
      }
    }
    // ---- stage V transposed: Vt[d][key], swizzled byte = (d*128+key*2) ^ ((d&7)<<4) ----
    #pragma unroll
    for (int pass=0; pass<2; pass++){
      int p = pass*256 + tid;          // 0..511
      int key = p >> 3, d0 = p & 7;
      short8 vv = *(const short8*)(Vg + ((size_t)(bh*2048 + kt*64 + key))*64 + d0*8);
      #pragma unroll
      for (int t=0;t<8;t++){
        int d = d0*8 + t;
        unsigned off = (unsigned)(d*128 + key*2) ^ (unsigned)((d&7)<<4);
        *(u16*)((char*)Vts + off) = (u16)vv[t];
      }
    }
    __syncthreads();

    // ---- QK^T: 16 queries x 64 keys ----
    f32x4 sc[4];
    #pragma unroll
    for (int nf=0;nf<4;nf++) sc[nf] = z4;
    #pragma unroll
    for (int ks=0;ks<2;ks++){
      short8 qf = ks ? qf1 : qf0;
      #pragma unroll
      for (int nf=0;nf<4;nf++){
        int key = nf*16 + c;
        unsigned off = (unsigned)(key*128 + ks*64 + g*16) ^ (unsigned)((key&7)<<4);
        short8 kb = *(const short8*)((const char*)Ks + off);
        sc[nf] = MFMA16(qf, kb, sc[nf]);
      }
    }

    float pb[4];
    #pragma unroll
    for (int nf=0;nf<4;nf++) pb[nf] = posb[bh*2048 + kt*64 + nf*16 + c];
    u64 mw[4];
    #pragma unroll
    for (int i=0;i<4;i++) mw[i] = pmask[((size_t)(b_*2048 + q0w + g*4 + i))*32 + kt];

    // ---- online softmax (per query row: 16 lanes share g; keys = nf*16+c) ----
    float pv_[4][4];
    #pragma unroll
    for (int i=0;i<4;i++){
      float t = -3e30f;
      #pragma unroll
      for (int nf=0;nf<4;nf++){
        float s = sc[nf][i]*0.125f + pb[nf];
        if (!((mw[i] >> (nf*16 + c)) & 1ull)) s = -1e30f;
        pv_[nf][i] = s;
        t = fmaxf(t, s);
      }
      t = fmaxf(t, __shfl_xor(t, 1));
      t = fmaxf(t, __shfl_xor(t, 2));
      t = fmaxf(t, __shfl_xor(t, 4));
      t = fmaxf(t, __shfl_xor(t, 8));
      float mn = fmaxf(mi[i], t);
      float al = __expf(mi[i] - mn);
      mi[i] = mn;
      float rs = 0.f;
      #pragma unroll
      for (int nf=0;nf<4;nf++){
        float e = __expf(pv_[nf][i] - mn);
        pv_[nf][i] = e;
        rs += e;
      }
      rs += __shfl_xor(rs, 1);
      rs += __shfl_xor(rs, 2);
      rs += __shfl_xor(rs, 4);
      rs += __shfl_xor(rs, 8);
      li[i] = li[i]*al + rs;
      #pragma unroll
      for (int db=0;db<4;db++) Oa[db][i] *= al;
    }

    // ---- P -> LDS (swizzled), row = q(0..15), col = key ----
    #pragma unroll
    for (int i=0;i<4;i++){
      int qr = g*4 + i;
      #pragma unroll
      for (int nf=0;nf<4;nf++){
        unsigned off = (unsigned)(qr*128 + (nf*16 + c)*2) ^ (unsigned)((qr&7)<<4);
        *(u16*)((char*)Pw + off) = f2bf(pv_[nf][i]);
      }
    }
    __syncthreads();

    // ---- PV: O[q][d] += sum_key P[q][key] * Vt[d][key] ----
    #pragma unroll
    for (int ks=0;ks<2;ks++){
      unsigned aoff = (unsigned)(c*128 + ks*64 + g*16) ^ (unsigned)((c&7)<<4);
      short8 pa = *(const short8*)((const char*)Pw + aoff);
      #pragma unroll
      for (int db=0;db<4;db++){
        int d = db*16 + c;
        unsigned boff = (unsigned)(d*128 + ks*64 + g*16) ^ (unsigned)((d&7)<<4);
        short8 vb = *(const short8*)((const char*)Vts + boff);
        Oa[db] = MFMA16(pa, vb, Oa[db]);
      }
    }
    __syncthreads();
  }

  // ---- epilogue: normalize, write (b,s,h*64+d) bf16 ----
  #pragma unroll
  for (int i=0;i<4;i++){
    float inv = 1.0f / li[i];
    int q = q0w + g*4 + i;
    size_t base = ((size_t)(b_*2048 + q))*1024 + h_*64;
    #pragma unroll
    for (int db=0;db<4;db++)
      AO[base + db*16 + c] = f2bf(Oa[db][i] * inv);
  }
}

// ---------------- output projection GEMM ----------------
__global__ __launch_bounds__(256) void k_out(const u16* __restrict__ A, const u16* __restrict__ W,
    const float* __restrict__ bo, float* __restrict__ out){
  __shared__ __align__(16) u16 As[128*32];
  __shared__ __align__(16) u16 Bs[128*32];
  const int bx = blockIdx.x, by = blockIdx.y;
  const int tid = threadIdx.x, wid = tid >> 6, lane = tid & 63;
  const int m0 = bx*128, n0 = by*128;
  const int wm = wid >> 1, wn = wid & 1;
  const int g8 = (lane >> 4)*8;

  f32x4 acc[4][4];
  f32x4 z4 = {0.f,0.f,0.f,0.f};
  #pragma unroll
  for (int mf=0;mf<4;mf++)
    #pragma unroll
    for (int nf=0;nf<4;nf++) acc[mf][nf] = z4;

  for (int kt=0; kt<32; kt++){
    #pragma unroll
    for (int jj=0;jj<2;jj++){
      int sp = wid*2 + jj;
      int p = sp*64 + lane;
      int row = p >> 2, c4 = p & 3;
      gload16(A + (size_t)(m0+row)*1024 + kt*32 + c4*8, &As[sp*512]);
      gload16(W + (size_t)(n0+row)*1024 + kt*32 + c4*8, &Bs[sp*512]);
    }
    __syncthreads();
    short8 a[4], b[4];
    #pragma unroll
    for (int mf=0;mf<4;mf++) a[mf] = *(const short8*)&As[(wm*64 + mf*16 + (lane&15))*32 + g8];
    #pragma unroll
    for (int nf=0;nf<4;nf++) b[nf] = *(const short8*)&Bs[(wn*64 + nf*16 + (lane&15))*32 + g8];
    #pragma unroll
    for (int mf=0;mf<4;mf++)
      #pragma unroll
      for (int nf=0;nf<4;nf++) acc[mf][nf] = MFMA16(a[mf], b[nf], acc[mf][nf]);
    __syncthreads();
  }

  #pragma unroll
  for (int nf=0;nf<4;nf++){
    int n = n0 + wn*64 + nf*16 + (lane & 15);
    float bb = bo[n];
    #pragma unroll
    for (int mf=0;mf<4;mf++)
      #pragma unroll
      for (int i=0;i<4;i++){
        int m = m0 + wm*64 + mf*16 + (lane>>4)*4 + i;
        out[(size_t)m*1024 + n] = acc[mf][nf][i] + bb;
      }
  }
}

extern "C" void kernel_launch(void* const* d_in, const int* in_sizes, int n_in,
                              void* d_out, int out_size, void* d_ws, size_t ws_size,
                              hipStream_t stream){
  const float* x    = (const float*)d_in[0];
  const float* pos  = (const float*)d_in[1];
  const int*   mask = (const int*)d_in[2];
  const float* wq   = (const float*)d_in[3];
  const float* bq   = (const float*)d_in[4];
  const float* wk   = (const float*)d_in[5];
  const float* bk   = (const float*)d_in[6];
  const float* wv   = (const float*)d_in[7];
  const float* bv   = (const float*)d_in[8];
  const float* wo   = (const float*)d_in[9];
  const float* bo   = (const float*)d_in[10];
  const float* wpos = (const float*)d_in[11];
  float* out = (float*)d_out;

  char* ws = (char*)d_ws;
  u16* xb   = (u16*)(ws);
  u16* wqb  = (u16*)(ws + ((size_t)8  << 20));
  u16* wkb  = (u16*)(ws + ((size_t)10 << 20));
  u16* wvb  = (u16*)(ws + ((size_t)12 << 20));
  u16* wob  = (u16*)(ws + ((size_t)14 << 20));
  u16* Qb   = (u16*)(ws + ((size_t)16 << 20));
  u16* Kb   = (u16*)(ws + ((size_t)24 << 20));
  u16* Vb   = (u16*)(ws + ((size_t)32 << 20));
  u16* AO   = (u16*)(ws + ((size_t)40 << 20));
  float* posb = (float*)(ws + ((size_t)48 << 20));
  u64* pm   = (u64*)(ws + ((size_t)49 << 20));

  k_prep<<<dim3(2048), dim3(256), 0, stream>>>(x, wq, wk, wv, wo, xb, wqb, wkb, wvb, wob);
  k_posb<<<dim3(1024), dim3(256), 0, stream>>>(pos, wpos, posb);
  k_mask<<<dim3(1024), dim3(256), 0, stream>>>(mask, pm);
  k_qkv<<<dim3(32,24), dim3(256), 0, stream>>>(xb, wqb, wkb, wvb, bq, bk, bv, Qb, Kb, Vb);
  k_attn<<<dim3(1024), dim3(256), 0, stream>>>(Qb, Kb, Vb, posb, pm, AO);
  k_out<<<dim3(32,8), dim3(256), 0, stream>>>(AO, wob, bo, out);
}

// Round 3
// 366.191 us; speedup vs baseline: 1.0904x; 1.0904x over previous
//
#include <hip/hip_runtime.h>
#include <stdint.h>

typedef unsigned short u16;
typedef unsigned int u32;
typedef unsigned long long u64;
typedef __attribute__((ext_vector_type(8))) short short8;
typedef __attribute__((ext_vector_type(4))) float f32x4;

#define MFMA16(a,b,c) __builtin_amdgcn_mfma_f32_16x16x32_bf16((a),(b),(c),0,0,0)

__device__ __forceinline__ u16 f2bf(float f){
  u32 u = __builtin_bit_cast(u32, f);
  u32 r = u + 0x7FFFu + ((u >> 16) & 1u);
  return (u16)(r >> 16);
}

__device__ __forceinline__ void gload16(const void* g, void* l){
  __builtin_amdgcn_global_load_lds((__attribute__((address_space(1))) void*)(uintptr_t)g,
                                   (__attribute__((address_space(3))) void*)l, 16, 0, 0);
}

// ---------------- prep: cast x + weights to bf16 ----------------
__global__ __launch_bounds__(256) void k_prep(const float* __restrict__ x,
    const float* __restrict__ wq, const float* __restrict__ wk,
    const float* __restrict__ wv, const float* __restrict__ wo,
    u16* __restrict__ xb, u16* __restrict__ wqb, u16* __restrict__ wkb,
    u16* __restrict__ wvb, u16* __restrict__ wob){
  for (int j = blockIdx.x*blockDim.x + threadIdx.x; j < 2097152; j += gridDim.x*blockDim.x){
    const float* src; u16* dst; int off;
    if (j < 1048576){ src = x; dst = xb; off = j; }
    else {
      int r = (j - 1048576) >> 18; off = (j - 1048576) & 262143;
      src = (r==0)?wq:(r==1)?wk:(r==2)?wv:wo;
      dst = (r==0)?wqb:(r==1)?wkb:(r==2)?wvb:wob;
    }
    float4 v = ((const float4*)src)[off];
    ushort4 o;
    o.x = f2bf(v.x); o.y = f2bf(v.y); o.z = f2bf(v.z); o.w = f2bf(v.w);
    ((ushort4*)dst)[off] = o;
  }
}

// ---------------- pos_bias[b,h,s] = dot(pos_emb[b,s,:], w_pos[h,:]) * log2(e) ----------------
__global__ __launch_bounds__(256) void k_posb(const float* __restrict__ pos,
    const float* __restrict__ wpos, float* __restrict__ posb){
  int row = blockIdx.x*4 + (threadIdx.x >> 6);   // (b*2048+s), 4096 rows
  int lane = threadIdx.x & 63;
  const float* pr = pos + (size_t)row*1024;
  float pv[16];
  #pragma unroll
  for (int t=0;t<4;t++){
    float4 v = ((const float4*)pr)[lane + 64*t];
    pv[4*t+0]=v.x; pv[4*t+1]=v.y; pv[4*t+2]=v.z; pv[4*t+3]=v.w;
  }
  int b = row >> 11, s = row & 2047;
  for (int h=0; h<16; h++){
    const float* wr = wpos + h*1024;
    float acc = 0.f;
    #pragma unroll
    for (int t=0;t<4;t++){
      float4 w = ((const float4*)wr)[lane + 64*t];
      acc += pv[4*t+0]*w.x + pv[4*t+1]*w.y + pv[4*t+2]*w.z + pv[4*t+3]*w.w;
    }
    #pragma unroll
    for (int m=1;m<64;m<<=1) acc += __shfl_xor(acc, m);
    if (lane == 0) posb[(b*16 + h)*2048 + s] = acc * 1.44269504f;
  }
}

// ---------------- pack mask to bits ----------------
__global__ __launch_bounds__(256) void k_mask(const int* __restrict__ mask, u64* __restrict__ pm){
  int wi = (blockIdx.x*blockDim.x + threadIdx.x) >> 6;
  int lane = threadIdx.x & 63;
  int nw = (gridDim.x*blockDim.x) >> 6;
  for (int w = wi; w < 131072; w += nw){
    int v = mask[(size_t)w*64 + lane];
    u64 bits = __ballot(v != 0);
    if (lane == 0) pm[w] = bits;
  }
}

// ---------------- fused QKV projection GEMM ----------------
// C = Xb(4096x1024) * W^T; Q,K -> (b,h,s,d) bf16 ; V -> TRANSPOSED (b,h,d,s) bf16
__global__ __launch_bounds__(256) void k_qkv(const u16* __restrict__ xb,
    const u16* __restrict__ wqb, const u16* __restrict__ wkb, const u16* __restrict__ wvb,
    const float* __restrict__ bq, const float* __restrict__ bk, const float* __restrict__ bv,
    u16* __restrict__ Q, u16* __restrict__ K, u16* __restrict__ V){
  __shared__ __align__(16) u16 As[128*32];
  __shared__ __align__(16) u16 Bs[128*32];
  const int bx = blockIdx.x, by = blockIdx.y;
  const int tid = threadIdx.x, wid = tid >> 6, lane = tid & 63;
  const int wsel = by >> 3;
  const u16* W = (wsel==0) ? wqb : (wsel==1 ? wkb : wvb);
  const float* bias = (wsel==0) ? bq : (wsel==1 ? bk : bv);
  u16* dst = (wsel==0) ? Q : (wsel==1 ? K : V);
  const int m0 = bx*128, n0 = (by & 7)*128;
  const int wm = wid >> 1, wn = wid & 1;
  const int g8 = (lane >> 4)*8;

  f32x4 acc[4][4];
  f32x4 z4 = {0.f,0.f,0.f,0.f};
  #pragma unroll
  for (int mf=0;mf<4;mf++)
    #pragma unroll
    for (int nf=0;nf<4;nf++) acc[mf][nf] = z4;

  for (int kt=0; kt<32; kt++){
    #pragma unroll
    for (int jj=0;jj<2;jj++){
      int sp = wid*2 + jj;
      int p = sp*64 + lane;
      int row = p >> 2, c4 = p & 3;
      gload16(xb + (size_t)(m0+row)*1024 + kt*32 + c4*8, &As[sp*512]);
      gload16(W  + (size_t)(n0+row)*1024 + kt*32 + c4*8, &Bs[sp*512]);
    }
    __syncthreads();
    short8 a[4], b[4];
    #pragma unroll
    for (int mf=0;mf<4;mf++) a[mf] = *(const short8*)&As[(wm*64 + mf*16 + (lane&15))*32 + g8];
    #pragma unroll
    for (int nf=0;nf<4;nf++) b[nf] = *(const short8*)&Bs[(wn*64 + nf*16 + (lane&15))*32 + g8];
    #pragma unroll
    for (int mf=0;mf<4;mf++)
      #pragma unroll
      for (int nf=0;nf<4;nf++) acc[mf][nf] = MFMA16(a[mf], b[nf], acc[mf][nf]);
    __syncthreads();
  }

  #pragma unroll
  for (int nf=0;nf<4;nf++){
    int nloc = n0 + wn*64 + nf*16 + (lane & 15);   // 0..1023 within this weight
    float bb = bias[nloc];
    int h = nloc >> 6, d = nloc & 63;
    #pragma unroll
    for (int mf=0;mf<4;mf++)
      #pragma unroll
      for (int i=0;i<4;i++){
        int m = m0 + wm*64 + mf*16 + (lane>>4)*4 + i;
        int bt = m >> 11, s = m & 2047;
        u16 val = f2bf(acc[mf][nf][i] + bb);
        if (wsel == 2)
          dst[((size_t)((bt*16 + h)*64 + d))*2048 + s] = val;      // V^T: (b,h,d,s)
        else
          dst[((size_t)((bt*16 + h)*2048 + s))*64 + d] = val;      // (b,h,s,d)
      }
  }
}

// ---------------- flash attention ----------------
// Per block: one (b,h), 64 queries (4 waves x 16). KV tile = 64.
// K LDS: [key][d] XOR-swizzled; Vt LDS: [d][key] XOR-swizzled — both staged
// via global_load_lds with pre-swizzled global source (same involution as read).
__global__ __launch_bounds__(256) void k_attn(const u16* __restrict__ Qg, const u16* __restrict__ Kg,
    const u16* __restrict__ Vtg, const float* __restrict__ posb, const u64* __restrict__ pmask,
    u16* __restrict__ AO){
  __shared__ __align__(16) u16 Ks[64*64];
  __shared__ __align__(16) u16 Vts[64*64];
  __shared__ __align__(16) u16 Ps[4*16*64];
  const int bid = blockIdx.x;
  const int bh = bid >> 5;       // 0..31, consecutive blocks share K/V for L2
  const int qt = bid & 31;
  const int b_ = bh >> 4;
  const int h_ = bh & 15;
  const int tid = threadIdx.x, wid = tid >> 6, lane = tid & 63;
  const int g = lane >> 4, c = lane & 15;
  const int q0w = qt*64 + wid*16;
  const float SC = 0.125f * 1.44269504f;   // 1/sqrt(64) * log2(e)

  short8 qf0, qf1;
  {
    const u16* qp = Qg + ((size_t)(bh*2048 + q0w + c))*64 + g*8;
    qf0 = *(const short8*)qp;
    qf1 = *(const short8*)(qp + 32);
  }
  f32x4 Oa[4];
  f32x4 z4 = {0.f,0.f,0.f,0.f};
  #pragma unroll
  for (int i=0;i<4;i++) Oa[i] = z4;
  float mi[4], li[4];
  #pragma unroll
  for (int i=0;i<4;i++){ mi[i] = -1e30f; li[i] = 0.f; }

  u16* Pw = Ps + wid*1024;

  for (int kt=0; kt<32; kt++){
    // ---- stage K (waves 0,1) and Vt (waves 2,3), pre-swizzled sources ----
    if (wid < 2){
      #pragma unroll
      for (int jj=0;jj<4;jj++){
        int sx = wid*4 + jj;
        int p = sx*64 + lane;
        int key = p >> 3, o16 = p & 7;
        gload16(Kg + ((size_t)(bh*2048 + kt*64 + key))*64 + (o16 ^ (key&7))*8, &Ks[sx*512]);
      }
    } else {
      #pragma unroll
      for (int jj=0;jj<4;jj++){
        int sv = (wid-2)*4 + jj;
        int p = sv*64 + lane;
        int d = p >> 3, o16 = p & 7;
        gload16(Vtg + ((size_t)(bh*64 + d))*2048 + kt*64 + (o16 ^ (d&7))*8, &Vts[sv*512]);
      }
    }
    __syncthreads();

    // ---- QK^T: 16 queries x 64 keys ----
    f32x4 sc[4];
    #pragma unroll
    for (int nf=0;nf<4;nf++) sc[nf] = z4;
    #pragma unroll
    for (int ks=0;ks<2;ks++){
      short8 qf = ks ? qf1 : qf0;
      #pragma unroll
      for (int nf=0;nf<4;nf++){
        int key = nf*16 + c;
        unsigned off = (unsigned)(key*128 + ks*64 + g*16) ^ (unsigned)((key&7)<<4);
        short8 kb = *(const short8*)((const char*)Ks + off);
        sc[nf] = MFMA16(qf, kb, sc[nf]);
      }
    }

    float pb[4];
    #pragma unroll
    for (int nf=0;nf<4;nf++) pb[nf] = posb[bh*2048 + kt*64 + nf*16 + c];
    u64 mw[4];
    #pragma unroll
    for (int i=0;i<4;i++) mw[i] = pmask[((size_t)(b_*2048 + q0w + g*4 + i))*32 + kt];

    // ---- online softmax in log2 domain, defer-max (THR=8) ----
    float pv_[4][4], rowmax[4];
    #pragma unroll
    for (int i=0;i<4;i++){
      u64 m = mw[i];
      #pragma unroll
      for (int nf=0;nf<4;nf++) pv_[nf][i] = sc[nf][i]*SC + pb[nf];
      if (m != ~0ull){
        #pragma unroll
        for (int nf=0;nf<4;nf++)
          if (!((m >> (nf*16 + c)) & 1ull)) pv_[nf][i] = -1e30f;
      }
      float t = fmaxf(fmaxf(pv_[0][i], pv_[1][i]), fmaxf(pv_[2][i], pv_[3][i]));
      t = fmaxf(t, __shfl_xor(t, 1));
      t = fmaxf(t, __shfl_xor(t, 2));
      t = fmaxf(t, __shfl_xor(t, 4));
      t = fmaxf(t, __shfl_xor(t, 8));
      rowmax[i] = t;
    }
    float need = rowmax[0] - mi[0];
    need = fmaxf(need, rowmax[1] - mi[1]);
    need = fmaxf(need, rowmax[2] - mi[2]);
    need = fmaxf(need, rowmax[3] - mi[3]);
    if (__any(need > 8.0f)){
      #pragma unroll
      for (int i=0;i<4;i++){
        float mn = fmaxf(mi[i], rowmax[i]);
        float al = __builtin_amdgcn_exp2f(mi[i] - mn);
        mi[i] = mn;
        li[i] *= al;
        #pragma unroll
        for (int db=0;db<4;db++) Oa[db][i] *= al;
      }
    }
    #pragma unroll
    for (int i=0;i<4;i++){
      float rs = 0.f;
      #pragma unroll
      for (int nf=0;nf<4;nf++){
        float e = __builtin_amdgcn_exp2f(pv_[nf][i] - mi[i]);
        pv_[nf][i] = e;
        rs += e;
      }
      rs += __shfl_xor(rs, 1);
      rs += __shfl_xor(rs, 2);
      rs += __shfl_xor(rs, 4);
      rs += __shfl_xor(rs, 8);
      li[i] += rs;
    }

    // ---- P -> LDS (swizzled), row = q(0..15), col = key ----
    #pragma unroll
    for (int i=0;i<4;i++){
      int qr = g*4 + i;
      #pragma unroll
      for (int nf=0;nf<4;nf++){
        unsigned off = (unsigned)(qr*128 + (nf*16 + c)*2) ^ (unsigned)((qr&7)<<4);
        *(u16*)((char*)Pw + off) = f2bf(pv_[nf][i]);
      }
    }
    __syncthreads();

    // ---- PV: O[q][d] += sum_key P[q][key] * Vt[d][key] ----
    #pragma unroll
    for (int ks=0;ks<2;ks++){
      unsigned aoff = (unsigned)(c*128 + ks*64 + g*16) ^ (unsigned)((c&7)<<4);
      short8 pa = *(const short8*)((const char*)Pw + aoff);
      #pragma unroll
      for (int db=0;db<4;db++){
        int d = db*16 + c;
        unsigned boff = (unsigned)(d*128 + ks*64 + g*16) ^ (unsigned)((d&7)<<4);
        short8 vb = *(const short8*)((const char*)Vts + boff);
        Oa[db] = MFMA16(pa, vb, Oa[db]);
      }
    }
    __syncthreads();
  }

  // ---- epilogue: normalize, write (b,s,h*64+d) bf16 ----
  #pragma unroll
  for (int i=0;i<4;i++){
    float inv = 1.0f / li[i];
    int q = q0w + g*4 + i;
    size_t base = ((size_t)(b_*2048 + q))*1024 + h_*64;
    #pragma unroll
    for (int db=0;db<4;db++)
      AO[base + db*16 + c] = f2bf(Oa[db][i] * inv);
  }
}

// ---------------- output projection GEMM ----------------
__global__ __launch_bounds__(256) void k_out(const u16* __restrict__ A, const u16* __restrict__ W,
    const float* __restrict__ bo, float* __restrict__ out){
  __shared__ __align__(16) u16 As[128*32];
  __shared__ __align__(16) u16 Bs[128*32];
  const int bx = blockIdx.x, by = blockIdx.y;
  const int tid = threadIdx.x, wid = tid >> 6, lane = tid & 63;
  const int m0 = bx*128, n0 = by*128;
  const int wm = wid >> 1, wn = wid & 1;
  const int g8 = (lane >> 4)*8;

  f32x4 acc[4][4];
  f32x4 z4 = {0.f,0.f,0.f,0.f};
  #pragma unroll
  for (int mf=0;mf<4;mf++)
    #pragma unroll
    for (int nf=0;nf<4;nf++) acc[mf][nf] = z4;

  for (int kt=0; kt<32; kt++){
    #pragma unroll
    for (int jj=0;jj<2;jj++){
      int sp = wid*2 + jj;
      int p = sp*64 + lane;
      int row = p >> 2, c4 = p & 3;
      gload16(A + (size_t)(m0+row)*1024 + kt*32 + c4*8, &As[sp*512]);
      gload16(W + (size_t)(n0+row)*1024 + kt*32 + c4*8, &Bs[sp*512]);
    }
    __syncthreads();
    short8 a[4], b[4];
    #pragma unroll
    for (int mf=0;mf<4;mf++) a[mf] = *(const short8*)&As[(wm*64 + mf*16 + (lane&15))*32 + g8];
    #pragma unroll
    for (int nf=0;nf<4;nf++) b[nf] = *(const short8*)&Bs[(wn*64 + nf*16 + (lane&15))*32 + g8];
    #pragma unroll
    for (int mf=0;mf<4;mf++)
      #pragma unroll
      for (int nf=0;nf<4;nf++) acc[mf][nf] = MFMA16(a[mf], b[nf], acc[mf][nf]);
    __syncthreads();
  }

  #pragma unroll
  for (int nf=0;nf<4;nf++){
    int n = n0 + wn*64 + nf*16 + (lane & 15);
    float bb = bo[n];
    #pragma unroll
    for (int mf=0;mf<4;mf++)
      #pragma unroll
      for (int i=0;i<4;i++){
        int m = m0 + wm*64 + mf*16 + (lane>>4)*4 + i;
        out[(size_t)m*1024 + n] = acc[mf][nf][i] + bb;
      }
  }
}

extern "C" void kernel_launch(void* const* d_in, const int* in_sizes, int n_in,
                              void* d_out, int out_size, void* d_ws, size_t ws_size,
                              hipStream_t stream){
  const float* x    = (const float*)d_in[0];
  const float* pos  = (const float*)d_in[1];
  const int*   mask = (const int*)d_in[2];
  const float* wq   = (const float*)d_in[3];
  const float* bq   = (const float*)d_in[4];
  const float* wk   = (const float*)d_in[5];
  const float* bk   = (const float*)d_in[6];
  const float* wv   = (const float*)d_in[7];
  const float* bv   = (const float*)d_in[8];
  const float* wo   = (const float*)d_in[9];
  const float* bo   = (const float*)d_in[10];
  const float* wpos = (const float*)d_in[11];
  float* out = (float*)d_out;

  char* ws = (char*)d_ws;
  u16* xb   = (u16*)(ws);
  u16* wqb  = (u16*)(ws + ((size_t)8  << 20));
  u16* wkb  = (u16*)(ws + ((size_t)10 << 20));
  u16* wvb  = (u16*)(ws + ((size_t)12 << 20));
  u16* wob  = (u16*)(ws + ((size_t)14 << 20));
  u16* Qb   = (u16*)(ws + ((size_t)16 << 20));
  u16* Kb   = (u16*)(ws + ((size_t)24 << 20));
  u16* Vtb  = (u16*)(ws + ((size_t)32 << 20));
  u16* AO   = (u16*)(ws + ((size_t)40 << 20));
  float* posb = (float*)(ws + ((size_t)48 << 20));
  u64* pm   = (u64*)(ws + ((size_t)49 << 20));

  k_prep<<<dim3(2048), dim3(256), 0, stream>>>(x, wq, wk, wv, wo, xb, wqb, wkb, wvb, wob);
  k_posb<<<dim3(1024), dim3(256), 0, stream>>>(pos, wpos, posb);
  k_mask<<<dim3(1024), dim3(256), 0, stream>>>(mask, pm);
  k_qkv<<<dim3(32,24), dim3(256), 0, stream>>>(xb, wqb, wkb, wvb, bq, bk, bv, Qb, Kb, Vtb);
  k_attn<<<dim3(1024), dim3(256), 0, stream>>>(Qb, Kb, Vtb, posb, pm, AO);
  k_out<<<dim3(32,8), dim3(256), 0, stream>>>(AO, wob, bo, out);
}

// Round 4
// 330.311 us; speedup vs baseline: 1.2089x; 1.1086x over previous
//
#include <hip/hip_runtime.h>
#include <stdint.h>

typedef unsigned short u16;
typedef unsigned int u32;
typedef unsigned long long u64;
typedef __attribute__((ext_vector_type(8))) short short8;
typedef __attribute__((ext_vector_type(4))) float f32x4;

#define MFMA16(a,b,c) __builtin_amdgcn_mfma_f32_16x16x32_bf16((a),(b),(c),0,0,0)

__device__ __forceinline__ u16 f2bf(float f){
  u32 u = __builtin_bit_cast(u32, f);
  u32 r = u + 0x7FFFu + ((u >> 16) & 1u);
  return (u16)(r >> 16);
}

__device__ __forceinline__ void gload16(const void* g, void* l){
  __builtin_amdgcn_global_load_lds((__attribute__((address_space(1))) void*)(uintptr_t)g,
                                   (__attribute__((address_space(3))) void*)l, 16, 0, 0);
}

// ---------------- prep: cast x + weights to bf16 ----------------
__global__ __launch_bounds__(256) void k_prep(const float* __restrict__ x,
    const float* __restrict__ wq, const float* __restrict__ wk,
    const float* __restrict__ wv, const float* __restrict__ wo,
    u16* __restrict__ xb, u16* __restrict__ wqb, u16* __restrict__ wkb,
    u16* __restrict__ wvb, u16* __restrict__ wob){
  for (int j = blockIdx.x*blockDim.x + threadIdx.x; j < 2097152; j += gridDim.x*blockDim.x){
    const float* src; u16* dst; int off;
    if (j < 1048576){ src = x; dst = xb; off = j; }
    else {
      int r = (j - 1048576) >> 18; off = (j - 1048576) & 262143;
      src = (r==0)?wq:(r==1)?wk:(r==2)?wv:wo;
      dst = (r==0)?wqb:(r==1)?wkb:(r==2)?wvb:wob;
    }
    float4 v = ((const float4*)src)[off];
    ushort4 o;
    o.x = f2bf(v.x); o.y = f2bf(v.y); o.z = f2bf(v.z); o.w = f2bf(v.w);
    ((ushort4*)dst)[off] = o;
  }
}

// ---------------- pos_bias[b,h,s] = dot(pos_emb[b,s,:], w_pos[h,:]) * log2(e) ----------------
__global__ __launch_bounds__(256) void k_posb(const float* __restrict__ pos,
    const float* __restrict__ wpos, float* __restrict__ posb){
  int row = blockIdx.x*4 + (threadIdx.x >> 6);   // (b*2048+s), 4096 rows
  int lane = threadIdx.x & 63;
  const float* pr = pos + (size_t)row*1024;
  float pv[16];
  #pragma unroll
  for (int t=0;t<4;t++){
    float4 v = ((const float4*)pr)[lane + 64*t];
    pv[4*t+0]=v.x; pv[4*t+1]=v.y; pv[4*t+2]=v.z; pv[4*t+3]=v.w;
  }
  int b = row >> 11, s = row & 2047;
  for (int h=0; h<16; h++){
    const float* wr = wpos + h*1024;
    float acc = 0.f;
    #pragma unroll
    for (int t=0;t<4;t++){
      float4 w = ((const float4*)wr)[lane + 64*t];
      acc += pv[4*t+0]*w.x + pv[4*t+1]*w.y + pv[4*t+2]*w.z + pv[4*t+3]*w.w;
    }
    #pragma unroll
    for (int m=1;m<64;m<<=1) acc += __shfl_xor(acc, m);
    if (lane == 0) posb[(b*16 + h)*2048 + s] = acc * 1.44269504f;
  }
}

// ---------------- pack mask to bits ----------------
__global__ __launch_bounds__(256) void k_mask(const int* __restrict__ mask, u64* __restrict__ pm){
  int wi = (blockIdx.x*blockDim.x + threadIdx.x) >> 6;
  int lane = threadIdx.x & 63;
  int nw = (gridDim.x*blockDim.x) >> 6;
  for (int w = wi; w < 131072; w += nw){
    int v = mask[(size_t)w*64 + lane];
    u64 bits = __ballot(v != 0);
    if (lane == 0) pm[w] = bits;
  }
}

// ---------------- fused QKV projection GEMM (dbuf, 1 barrier/tile) ----------------
// C = Xb(4096x1024) * W^T; Q,K -> (b,h,s,d) bf16 ; V -> TRANSPOSED (b,h,d,s) bf16
__global__ __launch_bounds__(256) void k_qkv(const u16* __restrict__ xb,
    const u16* __restrict__ wqb, const u16* __restrict__ wkb, const u16* __restrict__ wvb,
    const float* __restrict__ bq, const float* __restrict__ bk, const float* __restrict__ bv,
    u16* __restrict__ Q, u16* __restrict__ K, u16* __restrict__ V){
  __shared__ __align__(16) u16 As[2][128*32];
  __shared__ __align__(16) u16 Bs[2][128*32];
  const int bx = blockIdx.x, by = blockIdx.y;
  const int tid = threadIdx.x, wid = tid >> 6, lane = tid & 63;
  const int wsel = by >> 3;
  const u16* W = (wsel==0) ? wqb : (wsel==1 ? wkb : wvb);
  const float* bias = (wsel==0) ? bq : (wsel==1 ? bk : bv);
  u16* dst = (wsel==0) ? Q : (wsel==1 ? K : V);
  const int m0 = bx*128, n0 = (by & 7)*128;
  const int wm = wid >> 1, wn = wid & 1;
  const int g8 = (lane >> 4)*8;

  auto stage = [&](int kt, int buf){
    #pragma unroll
    for (int jj=0;jj<2;jj++){
      int sp = wid*2 + jj;
      int p = sp*64 + lane;
      int row = p >> 2, c4 = p & 3;
      gload16(xb + (size_t)(m0+row)*1024 + kt*32 + c4*8, &As[buf][sp*512]);
      gload16(W  + (size_t)(n0+row)*1024 + kt*32 + c4*8, &Bs[buf][sp*512]);
    }
  };

  f32x4 acc[4][4];
  f32x4 z4 = {0.f,0.f,0.f,0.f};
  #pragma unroll
  for (int mf=0;mf<4;mf++)
    #pragma unroll
    for (int nf=0;nf<4;nf++) acc[mf][nf] = z4;

  stage(0, 0);
  __syncthreads();
  for (int kt=0; kt<32; kt++){
    int cur = kt & 1;
    if (kt+1 < 32) stage(kt+1, cur^1);
    short8 a[4], b[4];
    #pragma unroll
    for (int mf=0;mf<4;mf++) a[mf] = *(const short8*)&As[cur][(wm*64 + mf*16 + (lane&15))*32 + g8];
    #pragma unroll
    for (int nf=0;nf<4;nf++) b[nf] = *(const short8*)&Bs[cur][(wn*64 + nf*16 + (lane&15))*32 + g8];
    #pragma unroll
    for (int mf=0;mf<4;mf++)
      #pragma unroll
      for (int nf=0;nf<4;nf++) acc[mf][nf] = MFMA16(a[mf], b[nf], acc[mf][nf]);
    __syncthreads();
  }

  #pragma unroll
  for (int nf=0;nf<4;nf++){
    int nloc = n0 + wn*64 + nf*16 + (lane & 15);   // 0..1023 within this weight
    float bb = bias[nloc];
    int h = nloc >> 6, d = nloc & 63;
    #pragma unroll
    for (int mf=0;mf<4;mf++)
      #pragma unroll
      for (int i=0;i<4;i++){
        int m = m0 + wm*64 + mf*16 + (lane>>4)*4 + i;
        int bt = m >> 11, s = m & 2047;
        u16 val = f2bf(acc[mf][nf][i] + bb);
        if (wsel == 2)
          dst[((size_t)((bt*16 + h)*64 + d))*2048 + s] = val;      // V^T: (b,h,d,s)
        else
          dst[((size_t)((bt*16 + h)*2048 + s))*64 + d] = val;      // (b,h,s,d)
      }
  }
}

// ---------------- flash attention (dbuf K/V, 1 barrier/tile, XCD swizzle) ----------------
__global__ __launch_bounds__(256) void k_attn(const u16* __restrict__ Qg, const u16* __restrict__ Kg,
    const u16* __restrict__ Vtg, const float* __restrict__ posb, const u64* __restrict__ pmask,
    u16* __restrict__ AO){
  __shared__ __align__(16) u16 Ks[2][64*64];
  __shared__ __align__(16) u16 Vts[2][64*64];
  __shared__ __align__(16) u16 Ps[4*16*64];
  const int bid0 = blockIdx.x;
  const int bid = (bid0 & 7)*128 + (bid0 >> 3);   // bijective XCD swizzle (1024 = 8*128)
  const int bh = bid >> 5;       // 4 bh per XCD -> K/V L2-resident
  const int qt = bid & 31;
  const int b_ = bh >> 4;
  const int h_ = bh & 15;
  const int tid = threadIdx.x, wid = tid >> 6, lane = tid & 63;
  const int g = lane >> 4, c = lane & 15;
  const int q0w = qt*64 + wid*16;
  const float SC = 0.125f * 1.44269504f;   // 1/sqrt(64) * log2(e)

  short8 qf0, qf1;
  {
    const u16* qp = Qg + ((size_t)(bh*2048 + q0w + c))*64 + g*8;
    qf0 = *(const short8*)qp;
    qf1 = *(const short8*)(qp + 32);
  }
  f32x4 Oa[4];
  f32x4 z4 = {0.f,0.f,0.f,0.f};
  #pragma unroll
  for (int i=0;i<4;i++) Oa[i] = z4;
  float mi[4], li[4];
  #pragma unroll
  for (int i=0;i<4;i++){ mi[i] = -1e30f; li[i] = 0.f; }

  u16* Pw = Ps + wid*1024;

  auto stage = [&](int kt, int buf){
    if (wid < 2){
      #pragma unroll
      for (int jj=0;jj<4;jj++){
        int sx = wid*4 + jj;
        int p = sx*64 + lane;
        int key = p >> 3, o16 = p & 7;
        gload16(Kg + ((size_t)(bh*2048 + kt*64 + key))*64 + (o16 ^ (key&7))*8, &Ks[buf][sx*512]);
      }
    } else {
      #pragma unroll
      for (int jj=0;jj<4;jj++){
        int sv = (wid-2)*4 + jj;
        int p = sv*64 + lane;
        int d = p >> 3, o16 = p & 7;
        gload16(Vtg + ((size_t)(bh*64 + d))*2048 + kt*64 + (o16 ^ (d&7))*8, &Vts[buf][sv*512]);
      }
    }
  };

  stage(0, 0);
  __syncthreads();

  for (int kt=0; kt<32; kt++){
    const int cur = kt & 1;
    if (kt+1 < 32) stage(kt+1, cur^1);

    // ---- QK^T: 16 queries x 64 keys ----
    f32x4 sc[4];
    #pragma unroll
    for (int nf=0;nf<4;nf++) sc[nf] = z4;
    #pragma unroll
    for (int ks=0;ks<2;ks++){
      short8 qf = ks ? qf1 : qf0;
      #pragma unroll
      for (int nf=0;nf<4;nf++){
        int key = nf*16 + c;
        unsigned off = (unsigned)(key*128 + ks*64 + g*16) ^ (unsigned)((key&7)<<4);
        short8 kb = *(const short8*)((const char*)&Ks[cur][0] + off);
        sc[nf] = MFMA16(qf, kb, sc[nf]);
      }
    }

    float pb[4];
    #pragma unroll
    for (int nf=0;nf<4;nf++) pb[nf] = posb[bh*2048 + kt*64 + nf*16 + c];
    u64 mw[4];
    #pragma unroll
    for (int i=0;i<4;i++) mw[i] = pmask[((size_t)(b_*2048 + q0w + g*4 + i))*32 + kt];

    // ---- online softmax, log2 domain, defer-max; li is per-lane partial ----
    float pv_[4][4], lmax[4];
    #pragma unroll
    for (int i=0;i<4;i++){
      u64 m = mw[i];
      #pragma unroll
      for (int nf=0;nf<4;nf++) pv_[nf][i] = sc[nf][i]*SC + pb[nf];
      if (m != ~0ull){
        #pragma unroll
        for (int nf=0;nf<4;nf++)
          if (!((m >> (nf*16 + c)) & 1ull)) pv_[nf][i] = -1e30f;
      }
      lmax[i] = fmaxf(fmaxf(pv_[0][i], pv_[1][i]), fmaxf(pv_[2][i], pv_[3][i]));
    }
    float need = fmaxf(fmaxf(lmax[0]-mi[0], lmax[1]-mi[1]),
                       fmaxf(lmax[2]-mi[2], lmax[3]-mi[3]));
    if (__any(need > 8.0f)){
      #pragma unroll
      for (int i=0;i<4;i++){
        float t = lmax[i];
        t = fmaxf(t, __shfl_xor(t, 1));
        t = fmaxf(t, __shfl_xor(t, 2));
        t = fmaxf(t, __shfl_xor(t, 4));
        t = fmaxf(t, __shfl_xor(t, 8));
        float mn = fmaxf(mi[i], t);
        float al = __builtin_amdgcn_exp2f(mi[i] - mn);
        mi[i] = mn;
        li[i] *= al;
        #pragma unroll
        for (int db=0;db<4;db++) Oa[db][i] *= al;
      }
    }
    #pragma unroll
    for (int i=0;i<4;i++){
      float rs = 0.f;
      #pragma unroll
      for (int nf=0;nf<4;nf++){
        float e = __builtin_amdgcn_exp2f(pv_[nf][i] - mi[i]);
        pv_[nf][i] = e;
        rs += e;
      }
      li[i] += rs;       // per-lane partial; reduced in epilogue
    }

    // ---- P -> LDS (swizzled, WAVE-PRIVATE: no barrier needed) ----
    #pragma unroll
    for (int i=0;i<4;i++){
      int qr = g*4 + i;
      #pragma unroll
      for (int nf=0;nf<4;nf++){
        unsigned off = (unsigned)(qr*128 + (nf*16 + c)*2) ^ (unsigned)((qr&7)<<4);
        *(u16*)((char*)Pw + off) = f2bf(pv_[nf][i]);
      }
    }

    // ---- PV: O[q][d] += sum_key P[q][key] * Vt[d][key] ----
    #pragma unroll
    for (int ks=0;ks<2;ks++){
      unsigned aoff = (unsigned)(c*128 + ks*64 + g*16) ^ (unsigned)((c&7)<<4);
      short8 pa = *(const short8*)((const char*)Pw + aoff);
      #pragma unroll
      for (int db=0;db<4;db++){
        int d = db*16 + c;
        unsigned boff = (unsigned)(d*128 + ks*64 + g*16) ^ (unsigned)((d&7)<<4);
        short8 vb = *(const short8*)((const char*)&Vts[cur][0] + boff);
        Oa[db] = MFMA16(pa, vb, Oa[db]);
      }
    }
    __syncthreads();   // one barrier/tile: drains prefetch + protects buffers
  }

  // ---- epilogue: reduce li, normalize, write (b,s,h*64+d) bf16 ----
  #pragma unroll
  for (int i=0;i<4;i++){
    float s = li[i];
    s += __shfl_xor(s, 1);
    s += __shfl_xor(s, 2);
    s += __shfl_xor(s, 4);
    s += __shfl_xor(s, 8);
    float inv = 1.0f / s;
    int q = q0w + g*4 + i;
    size_t base = ((size_t)(b_*2048 + q))*1024 + h_*64;
    #pragma unroll
    for (int db=0;db<4;db++)
      AO[base + db*16 + c] = f2bf(Oa[db][i] * inv);
  }
}

// ---------------- output projection GEMM (dbuf, 1 barrier/tile) ----------------
__global__ __launch_bounds__(256) void k_out(const u16* __restrict__ A, const u16* __restrict__ W,
    const float* __restrict__ bo, float* __restrict__ out){
  __shared__ __align__(16) u16 As[2][128*32];
  __shared__ __align__(16) u16 Bs[2][128*32];
  const int bx = blockIdx.x, by = blockIdx.y;
  const int tid = threadIdx.x, wid = tid >> 6, lane = tid & 63;
  const int m0 = bx*128, n0 = by*128;
  const int wm = wid >> 1, wn = wid & 1;
  const int g8 = (lane >> 4)*8;

  auto stage = [&](int kt, int buf){
    #pragma unroll
    for (int jj=0;jj<2;jj++){
      int sp = wid*2 + jj;
      int p = sp*64 + lane;
      int row = p >> 2, c4 = p & 3;
      gload16(A + (size_t)(m0+row)*1024 + kt*32 + c4*8, &As[buf][sp*512]);
      gload16(W + (size_t)(n0+row)*1024 + kt*32 + c4*8, &Bs[buf][sp*512]);
    }
  };

  f32x4 acc[4][4];
  f32x4 z4 = {0.f,0.f,0.f,0.f};
  #pragma unroll
  for (int mf=0;mf<4;mf++)
    #pragma unroll
    for (int nf=0;nf<4;nf++) acc[mf][nf] = z4;

  stage(0, 0);
  __syncthreads();
  for (int kt=0; kt<32; kt++){
    int cur = kt & 1;
    if (kt+1 < 32) stage(kt+1, cur^1);
    short8 a[4], b[4];
    #pragma unroll
    for (int mf=0;mf<4;mf++) a[mf] = *(const short8*)&As[cur][(wm*64 + mf*16 + (lane&15))*32 + g8];
    #pragma unroll
    for (int nf=0;nf<4;nf++) b[nf] = *(const short8*)&Bs[cur][(wn*64 + nf*16 + (lane&15))*32 + g8];
    #pragma unroll
    for (int mf=0;mf<4;mf++)
      #pragma unroll
      for (int nf=0;nf<4;nf++) acc[mf][nf] = MFMA16(a[mf], b[nf], acc[mf][nf]);
    __syncthreads();
  }

  #pragma unroll
  for (int nf=0;nf<4;nf++){
    int n = n0 + wn*64 + nf*16 + (lane & 15);
    float bb = bo[n];
    #pragma unroll
    for (int mf=0;mf<4;mf++)
      #pragma unroll
      for (int i=0;i<4;i++){
        int m = m0 + wm*64 + mf*16 + (lane>>4)*4 + i;
        out[(size_t)m*1024 + n] = acc[mf][nf][i] + bb;
      }
  }
}

extern "C" void kernel_launch(void* const* d_in, const int* in_sizes, int n_in,
                              void* d_out, int out_size, void* d_ws, size_t ws_size,
                              hipStream_t stream){
  const float* x    = (const float*)d_in[0];
  const float* pos  = (const float*)d_in[1];
  const int*   mask = (const int*)d_in[2];
  const float* wq   = (const float*)d_in[3];
  const float* bq   = (const float*)d_in[4];
  const float* wk   = (const float*)d_in[5];
  const float* bk   = (const float*)d_in[6];
  const float* wv   = (const float*)d_in[7];
  const float* bv   = (const float*)d_in[8];
  const float* wo   = (const float*)d_in[9];
  const float* bo   = (const float*)d_in[10];
  const float* wpos = (const float*)d_in[11];
  float* out = (float*)d_out;

  char* ws = (char*)d_ws;
  u16* xb   = (u16*)(ws);
  u16* wqb  = (u16*)(ws + ((size_t)8  << 20));
  u16* wkb  = (u16*)(ws + ((size_t)10 << 20));
  u16* wvb  = (u16*)(ws + ((size_t)12 << 20));
  u16* wob  = (u16*)(ws + ((size_t)14 << 20));
  u16* Qb   = (u16*)(ws + ((size_t)16 << 20));
  u16* Kb   = (u16*)(ws + ((size_t)24 << 20));
  u16* Vtb  = (u16*)(ws + ((size_t)32 << 20));
  u16* AO   = (u16*)(ws + ((size_t)40 << 20));
  float* posb = (float*)(ws + ((size_t)48 << 20));
  u64* pm   = (u64*)(ws + ((size_t)49 << 20));

  k_prep<<<dim3(2048), dim3(256), 0, stream>>>(x, wq, wk, wv, wo, xb, wqb, wkb, wvb, wob);
  k_posb<<<dim3(1024), dim3(256), 0, stream>>>(pos, wpos, posb);
  k_mask<<<dim3(1024), dim3(256), 0, stream>>>(mask, pm);
  k_qkv<<<dim3(32,24), dim3(256), 0, stream>>>(xb, wqb, wkb, wvb, bq, bk, bv, Qb, Kb, Vtb);
  k_attn<<<dim3(1024), dim3(256), 0, stream>>>(Qb, Kb, Vtb, posb, pm, AO);
  k_out<<<dim3(32,8), dim3(256), 0, stream>>>(AO, wob, bo, out);
}

// Round 5
// 312.148 us; speedup vs baseline: 1.2792x; 1.0582x over previous
//
#include <hip/hip_runtime.h>
#include <stdint.h>

typedef unsigned short u16;
typedef unsigned int u32;
typedef unsigned long long u64;
typedef __attribute__((ext_vector_type(8))) short short8;
typedef __attribute__((ext_vector_type(4))) float f32x4;

#define MFMA16(a,b,c) __builtin_amdgcn_mfma_f32_16x16x32_bf16((a),(b),(c),0,0,0)

__device__ __forceinline__ u16 f2bf(float f){
  u32 u = __builtin_bit_cast(u32, f);
  u32 r = u + 0x7FFFu + ((u >> 16) & 1u);
  return (u16)(r >> 16);
}

__device__ __forceinline__ u32 pk_bf16(float lo, float hi){
  u32 w;
  asm("v_cvt_pk_bf16_f32 %0, %1, %2" : "=v"(w) : "v"(lo), "v"(hi));
  return w;
}

__device__ __forceinline__ void gload16(const void* g, void* l){
  __builtin_amdgcn_global_load_lds((__attribute__((address_space(1))) void*)(uintptr_t)g,
                                   (__attribute__((address_space(3))) void*)l, 16, 0, 0);
}

// ---------------- fused prep: cast to bf16 | pos_bias | mask pack ----------------
// blocks 0..2047: cast x+weights; 2048..3071: posb; 3072..4095: mask
__global__ __launch_bounds__(256) void k_prep(const float* __restrict__ x,
    const float* __restrict__ wq, const float* __restrict__ wk,
    const float* __restrict__ wv, const float* __restrict__ wo,
    const float* __restrict__ pos, const float* __restrict__ wpos,
    const int* __restrict__ mask,
    u16* __restrict__ xb, u16* __restrict__ wqb, u16* __restrict__ wkb,
    u16* __restrict__ wvb, u16* __restrict__ wob,
    float* __restrict__ posb, u64* __restrict__ pm){
  const int bx = blockIdx.x;
  if (bx < 2048){
    for (int j = bx*256 + threadIdx.x; j < 2097152; j += 2048*256){
      const float* src; u16* dst; int off;
      if (j < 1048576){ src = x; dst = xb; off = j; }
      else {
        int r = (j - 1048576) >> 18; off = (j - 1048576) & 262143;
        src = (r==0)?wq:(r==1)?wk:(r==2)?wv:wo;
        dst = (r==0)?wqb:(r==1)?wkb:(r==2)?wvb:wob;
      }
      float4 v = ((const float4*)src)[off];
      ushort4 o;
      o.x = f2bf(v.x); o.y = f2bf(v.y); o.z = f2bf(v.z); o.w = f2bf(v.w);
      ((ushort4*)dst)[off] = o;
    }
  } else if (bx < 3072){
    int row = (bx - 2048)*4 + (threadIdx.x >> 6);   // (b*2048+s), 4096 rows
    int lane = threadIdx.x & 63;
    const float* pr = pos + (size_t)row*1024;
    float pv[16];
    #pragma unroll
    for (int t=0;t<4;t++){
      float4 v = ((const float4*)pr)[lane + 64*t];
      pv[4*t+0]=v.x; pv[4*t+1]=v.y; pv[4*t+2]=v.z; pv[4*t+3]=v.w;
    }
    int b = row >> 11, s = row & 2047;
    for (int h=0; h<16; h++){
      const float* wr = wpos + h*1024;
      float acc = 0.f;
      #pragma unroll
      for (int t=0;t<4;t++){
        float4 w = ((const float4*)wr)[lane + 64*t];
        acc += pv[4*t+0]*w.x + pv[4*t+1]*w.y + pv[4*t+2]*w.z + pv[4*t+3]*w.w;
      }
      #pragma unroll
      for (int m=1;m<64;m<<=1) acc += __shfl_xor(acc, m);
      if (lane == 0) posb[(b*16 + h)*2048 + s] = acc * 1.44269504f;
    }
  } else {
    int lb = bx - 3072;
    int wi = (lb*256 + threadIdx.x) >> 6;
    int lane = threadIdx.x & 63;
    for (int w = wi; w < 131072; w += (1024*256)>>6){
      int v = mask[(size_t)w*64 + lane];
      u64 bits = __ballot(v != 0);
      if (lane == 0) pm[w] = bits;
    }
  }
}

// ---------------- fused QKV projection GEMM (dbuf, 1 barrier/tile) ----------------
// C = Xb(4096x1024) * W^T; Q,K -> (b,h,s,d) bf16 ; V -> TRANSPOSED (b,h,d,s) bf16
__global__ __launch_bounds__(256) void k_qkv(const u16* __restrict__ xb,
    const u16* __restrict__ wqb, const u16* __restrict__ wkb, const u16* __restrict__ wvb,
    const float* __restrict__ bq, const float* __restrict__ bk, const float* __restrict__ bv,
    u16* __restrict__ Q, u16* __restrict__ K, u16* __restrict__ V){
  __shared__ __align__(16) u16 As[2][128*32];
  __shared__ __align__(16) u16 Bs[2][128*32];
  const int bx = blockIdx.x, by = blockIdx.y;
  const int tid = threadIdx.x, wid = tid >> 6, lane = tid & 63;
  const int wsel = by >> 3;
  const u16* W = (wsel==0) ? wqb : (wsel==1 ? wkb : wvb);
  const float* bias = (wsel==0) ? bq : (wsel==1 ? bk : bv);
  u16* dst = (wsel==0) ? Q : (wsel==1 ? K : V);
  const int m0 = bx*128, n0 = (by & 7)*128;
  const int wm = wid >> 1, wn = wid & 1;
  const int g8 = (lane >> 4)*8;

  auto stage = [&](int kt, int buf){
    #pragma unroll
    for (int jj=0;jj<2;jj++){
      int sp = wid*2 + jj;
      int p = sp*64 + lane;
      int row = p >> 2, c4 = p & 3;
      gload16(xb + (size_t)(m0+row)*1024 + kt*32 + c4*8, &As[buf][sp*512]);
      gload16(W  + (size_t)(n0+row)*1024 + kt*32 + c4*8, &Bs[buf][sp*512]);
    }
  };

  f32x4 acc[4][4];
  f32x4 z4 = {0.f,0.f,0.f,0.f};
  #pragma unroll
  for (int mf=0;mf<4;mf++)
    #pragma unroll
    for (int nf=0;nf<4;nf++) acc[mf][nf] = z4;

  stage(0, 0);
  __syncthreads();
  for (int kt=0; kt<32; kt++){
    int cur = kt & 1;
    if (kt+1 < 32) stage(kt+1, cur^1);
    short8 a[4], b[4];
    #pragma unroll
    for (int mf=0;mf<4;mf++) a[mf] = *(const short8*)&As[cur][(wm*64 + mf*16 + (lane&15))*32 + g8];
    #pragma unroll
    for (int nf=0;nf<4;nf++) b[nf] = *(const short8*)&Bs[cur][(wn*64 + nf*16 + (lane&15))*32 + g8];
    #pragma unroll
    for (int mf=0;mf<4;mf++)
      #pragma unroll
      for (int nf=0;nf<4;nf++) acc[mf][nf] = MFMA16(a[mf], b[nf], acc[mf][nf]);
    __syncthreads();
  }

  #pragma unroll
  for (int nf=0;nf<4;nf++){
    int nloc = n0 + wn*64 + nf*16 + (lane & 15);   // 0..1023 within this weight
    float bb = bias[nloc];
    int h = nloc >> 6, d = nloc & 63;
    #pragma unroll
    for (int mf=0;mf<4;mf++)
      #pragma unroll
      for (int i=0;i<4;i++){
        int m = m0 + wm*64 + mf*16 + (lane>>4)*4 + i;
        int bt = m >> 11, s = m & 2047;
        u16 val = f2bf(acc[mf][nf][i] + bb);
        if (wsel == 2)
          dst[((size_t)((bt*16 + h)*64 + d))*2048 + s] = val;      // V^T: (b,h,d,s)
        else
          dst[((size_t)((bt*16 + h)*2048 + s))*64 + d] = val;      // (b,h,s,d)
      }
  }
}

// ---------------- flash attention ----------------
// Ks rows PERMUTED: row r holds key tau(r) = 2*(r&15) + ((r>>4)&1) + (r&32).
// => lane c's 4 scores are keys {2c,2c+1,2c+32,2c+33}: packable pairs, and the
//    packed P lands in NATURAL key order (element e = key e), so PV unchanged.
__global__ __launch_bounds__(256) void k_attn(const u16* __restrict__ Qg, const u16* __restrict__ Kg,
    const u16* __restrict__ Vtg, const float* __restrict__ posb, const u64* __restrict__ pmask,
    u16* __restrict__ AO){
  __shared__ __align__(16) u16 Ks[2][64*64];
  __shared__ __align__(16) u16 Vts[2][64*64];
  __shared__ __align__(16) u16 Ps[4*16*64];
  const int bid0 = blockIdx.x;
  const int bid = (bid0 & 7)*128 + (bid0 >> 3);   // bijective XCD swizzle (1024 = 8*128)
  const int bh = bid >> 5;       // 4 bh per XCD -> K/V L2-resident
  const int qt = bid & 31;
  const int b_ = bh >> 4;
  const int h_ = bh & 15;
  const int tid = threadIdx.x, wid = tid >> 6, lane = tid & 63;
  const int g = lane >> 4, c = lane & 15;
  const int q0w = qt*64 + wid*16;
  const float SC = 0.125f * 1.44269504f;   // 1/sqrt(64) * log2(e)

  short8 qf0, qf1;
  {
    const u16* qp = Qg + ((size_t)(bh*2048 + q0w + c))*64 + g*8;
    qf0 = *(const short8*)qp;
    qf1 = *(const short8*)(qp + 32);
  }
  f32x4 Oa[4];
  f32x4 z4 = {0.f,0.f,0.f,0.f};
  #pragma unroll
  for (int i=0;i<4;i++) Oa[i] = z4;
  float mi[4], li[4];
  #pragma unroll
  for (int i=0;i<4;i++){ mi[i] = -1e30f; li[i] = 0.f; }

  u16* Pw = Ps + wid*1024;

  auto stage = [&](int kt, int buf){
    if (wid < 2){
      #pragma unroll
      for (int jj=0;jj<4;jj++){
        int sx = wid*4 + jj;
        int p = sx*64 + lane;
        int r = p >> 3, o16 = p & 7;
        int tau = 2*(r&15) + ((r>>4)&1) + (r&32);
        gload16(Kg + ((size_t)(bh*2048 + kt*64 + tau))*64 + (o16 ^ (r&7))*8, &Ks[buf][sx*512]);
      }
    } else {
      #pragma unroll
      for (int jj=0;jj<4;jj++){
        int sv = (wid-2)*4 + jj;
        int p = sv*64 + lane;
        int d = p >> 3, o16 = p & 7;
        gload16(Vtg + ((size_t)(bh*64 + d))*2048 + kt*64 + (o16 ^ (d&7))*8, &Vts[buf][sv*512]);
      }
    }
  };

  stage(0, 0);
  __syncthreads();

  for (int kt=0; kt<32; kt++){
    const int cur = kt & 1;
    if (kt+1 < 32) stage(kt+1, cur^1);

    // ---- QK^T: 16 queries x 64 keys (Ks row nf*16+c = key kappa(nf)) ----
    f32x4 sc[4];
    #pragma unroll
    for (int nf=0;nf<4;nf++) sc[nf] = z4;
    __builtin_amdgcn_s_setprio(1);
    #pragma unroll
    for (int ks=0;ks<2;ks++){
      short8 qf = ks ? qf1 : qf0;
      #pragma unroll
      for (int nf=0;nf<4;nf++){
        int r = nf*16 + c;
        unsigned off = (unsigned)(r*128 + ks*64 + g*16) ^ (unsigned)((r&7)<<4);
        short8 kb = *(const short8*)((const char*)&Ks[cur][0] + off);
        sc[nf] = MFMA16(qf, kb, sc[nf]);
      }
    }
    __builtin_amdgcn_s_setprio(0);

    // pos bias for keys 2c,2c+1 and 2c+32,2c+33
    float2 pb01 = *(const float2*)&posb[bh*2048 + kt*64 + 2*c];
    float2 pb23 = *(const float2*)&posb[bh*2048 + kt*64 + 32 + 2*c];
    u64 mw[4];
    #pragma unroll
    for (int i=0;i<4;i++) mw[i] = pmask[((size_t)(b_*2048 + q0w + g*4 + i))*32 + kt];

    // ---- online softmax, log2 domain, defer-max; li per-lane partial ----
    float pv_[4][4], lmax[4];
    #pragma unroll
    for (int i=0;i<4;i++){
      pv_[0][i] = sc[0][i]*SC + pb01.x;
      pv_[1][i] = sc[1][i]*SC + pb01.y;
      pv_[2][i] = sc[2][i]*SC + pb23.x;
      pv_[3][i] = sc[3][i]*SC + pb23.y;
      u64 m = mw[i];
      if (m != ~0ull){
        u32 lo = (u32)(m >> (2*c));
        u32 hi = (u32)(m >> (2*c + 32));
        if (!(lo & 1u)) pv_[0][i] = -1e30f;
        if (!(lo & 2u)) pv_[1][i] = -1e30f;
        if (!(hi & 1u)) pv_[2][i] = -1e30f;
        if (!(hi & 2u)) pv_[3][i] = -1e30f;
      }
      lmax[i] = fmaxf(fmaxf(pv_[0][i], pv_[1][i]), fmaxf(pv_[2][i], pv_[3][i]));
    }
    float need = fmaxf(fmaxf(lmax[0]-mi[0], lmax[1]-mi[1]),
                       fmaxf(lmax[2]-mi[2], lmax[3]-mi[3]));
    if (__any(need > 8.0f)){
      #pragma unroll
      for (int i=0;i<4;i++){
        float t = lmax[i];
        t = fmaxf(t, __shfl_xor(t, 1));
        t = fmaxf(t, __shfl_xor(t, 2));
        t = fmaxf(t, __shfl_xor(t, 4));
        t = fmaxf(t, __shfl_xor(t, 8));
        float mn = fmaxf(mi[i], t);
        float al = __builtin_amdgcn_exp2f(mi[i] - mn);
        mi[i] = mn;
        li[i] *= al;
        #pragma unroll
        for (int db=0;db<4;db++) Oa[db][i] *= al;
      }
    }
    #pragma unroll
    for (int i=0;i<4;i++){
      float rs = 0.f;
      #pragma unroll
      for (int nf=0;nf<4;nf++){
        float e = __builtin_amdgcn_exp2f(pv_[nf][i] - mi[i]);
        pv_[nf][i] = e;
        rs += e;
      }
      li[i] += rs;
    }

    // ---- P -> LDS packed (keys 2c,2c+1 | 2c+32,2c+33), natural key order ----
    #pragma unroll
    for (int i=0;i<4;i++){
      int qr = g*4 + i;
      u32 w0 = pk_bf16(pv_[0][i], pv_[1][i]);
      u32 w1 = pk_bf16(pv_[2][i], pv_[3][i]);
      unsigned o0 = (unsigned)(qr*128 + 4*c) ^ (unsigned)((qr&7)<<4);
      unsigned o1 = (unsigned)(qr*128 + 64 + 4*c) ^ (unsigned)((qr&7)<<4);
      *(u32*)((char*)Pw + o0) = w0;
      *(u32*)((char*)Pw + o1) = w1;
    }

    // ---- PV: O[q][d] += sum_key P[q][key] * Vt[d][key] ----
    __builtin_amdgcn_s_setprio(1);
    #pragma unroll
    for (int ks=0;ks<2;ks++){
      unsigned aoff = (unsigned)(c*128 + ks*64 + g*16) ^ (unsigned)((c&7)<<4);
      short8 pa = *(const short8*)((const char*)Pw + aoff);
      #pragma unroll
      for (int db=0;db<4;db++){
        int d = db*16 + c;
        unsigned boff = (unsigned)(d*128 + ks*64 + g*16) ^ (unsigned)((d&7)<<4);
        short8 vb = *(const short8*)((const char*)&Vts[cur][0] + boff);
        Oa[db] = MFMA16(pa, vb, Oa[db]);
      }
    }
    __builtin_amdgcn_s_setprio(0);
    __syncthreads();   // one barrier/tile: drains prefetch + protects buffers
  }

  // ---- epilogue: reduce li, normalize, write (b,s,h*64+d) bf16 ----
  #pragma unroll
  for (int i=0;i<4;i++){
    float s = li[i];
    s += __shfl_xor(s, 1);
    s += __shfl_xor(s, 2);
    s += __shfl_xor(s, 4);
    s += __shfl_xor(s, 8);
    float inv = 1.0f / s;
    int q = q0w + g*4 + i;
    size_t base = ((size_t)(b_*2048 + q))*1024 + h_*64;
    #pragma unroll
    for (int db=0;db<4;db++)
      AO[base + db*16 + c] = f2bf(Oa[db][i] * inv);
  }
}

// ---------------- output projection GEMM (dbuf, 1 barrier/tile) ----------------
__global__ __launch_bounds__(256) void k_out(const u16* __restrict__ A, const u16* __restrict__ W,
    const float* __restrict__ bo, float* __restrict__ out){
  __shared__ __align__(16) u16 As[2][128*32];
  __shared__ __align__(16) u16 Bs[2][128*32];
  const int bx = blockIdx.x, by = blockIdx.y;
  const int tid = threadIdx.x, wid = tid >> 6, lane = tid & 63;
  const int m0 = bx*128, n0 = by*128;
  const int wm = wid >> 1, wn = wid & 1;
  const int g8 = (lane >> 4)*8;

  auto stage = [&](int kt, int buf){
    #pragma unroll
    for (int jj=0;jj<2;jj++){
      int sp = wid*2 + jj;
      int p = sp*64 + lane;
      int row = p >> 2, c4 = p & 3;
      gload16(A + (size_t)(m0+row)*1024 + kt*32 + c4*8, &As[buf][sp*512]);
      gload16(W + (size_t)(n0+row)*1024 + kt*32 + c4*8, &Bs[buf][sp*512]);
    }
  };

  f32x4 acc[4][4];
  f32x4 z4 = {0.f,0.f,0.f,0.f};
  #pragma unroll
  for (int mf=0;mf<4;mf++)
    #pragma unroll
    for (int nf=0;nf<4;nf++) acc[mf][nf] = z4;

  stage(0, 0);
  __syncthreads();
  for (int kt=0; kt<32; kt++){
    int cur = kt & 1;
    if (kt+1 < 32) stage(kt+1, cur^1);
    short8 a[4], b[4];
    #pragma unroll
    for (int mf=0;mf<4;mf++) a[mf] = *(const short8*)&As[cur][(wm*64 + mf*16 + (lane&15))*32 + g8];
    #pragma unroll
    for (int nf=0;nf<4;nf++) b[nf] = *(const short8*)&Bs[cur][(wn*64 + nf*16 + (lane&15))*32 + g8];
    #pragma unroll
    for (int mf=0;mf<4;mf++)
      #pragma unroll
      for (int nf=0;nf<4;nf++) acc[mf][nf] = MFMA16(a[mf], b[nf], acc[mf][nf]);
    __syncthreads();
  }

  #pragma unroll
  for (int nf=0;nf<4;nf++){
    int n = n0 + wn*64 + nf*16 + (lane & 15);
    float bb = bo[n];
    #pragma unroll
    for (int mf=0;mf<4;mf++)
      #pragma unroll
      for (int i=0;i<4;i++){
        int m = m0 + wm*64 + mf*16 + (lane>>4)*4 + i;
        out[(size_t)m*1024 + n] = acc[mf][nf][i] + bb;
      }
  }
}

extern "C" void kernel_launch(void* const* d_in, const int* in_sizes, int n_in,
                              void* d_out, int out_size, void* d_ws, size_t ws_size,
                              hipStream_t stream){
  const float* x    = (const float*)d_in[0];
  const float* pos  = (const float*)d_in[1];
  const int*   mask = (const int*)d_in[2];
  const float* wq   = (const float*)d_in[3];
  const float* bq   = (const float*)d_in[4];
  const float* wk   = (const float*)d_in[5];
  const float* bk   = (const float*)d_in[6];
  const float* wv   = (const float*)d_in[7];
  const float* bv   = (const float*)d_in[8];
  const float* wo   = (const float*)d_in[9];
  const float* bo   = (const float*)d_in[10];
  const float* wpos = (const float*)d_in[11];
  float* out = (float*)d_out;

  char* ws = (char*)d_ws;
  u16* xb   = (u16*)(ws);
  u16* wqb  = (u16*)(ws + ((size_t)8  << 20));
  u16* wkb  = (u16*)(ws + ((size_t)10 << 20));
  u16* wvb  = (u16*)(ws + ((size_t)12 << 20));
  u16* wob  = (u16*)(ws + ((size_t)14 << 20));
  u16* Qb   = (u16*)(ws + ((size_t)16 << 20));
  u16* Kb   = (u16*)(ws + ((size_t)24 << 20));
  u16* Vtb  = (u16*)(ws + ((size_t)32 << 20));
  u16* AO   = (u16*)(ws + ((size_t)40 << 20));
  float* posb = (float*)(ws + ((size_t)48 << 20));
  u64* pm   = (u64*)(ws + ((size_t)49 << 20));

  k_prep<<<dim3(4096), dim3(256), 0, stream>>>(x, wq, wk, wv, wo, pos, wpos, mask,
                                               xb, wqb, wkb, wvb, wob, posb, pm);
  k_qkv<<<dim3(32,24), dim3(256), 0, stream>>>(xb, wqb, wkb, wvb, bq, bk, bv, Qb, Kb, Vtb);
  k_attn<<<dim3(1024), dim3(256), 0, stream>>>(Qb, Kb, Vtb, posb, pm, AO);
  k_out<<<dim3(32,8), dim3(256), 0, stream>>>(AO, wob, bo, out);
}

// Round 6
// 294.563 us; speedup vs baseline: 1.3556x; 1.0597x over previous
//
#include <hip/hip_runtime.h>
#include <stdint.h>

typedef unsigned short u16;
typedef unsigned int u32;
typedef unsigned long long u64;
typedef __attribute__((ext_vector_type(8))) short short8;
typedef __attribute__((ext_vector_type(4))) float f32x4;

#define MFMA16(a,b,c) __builtin_amdgcn_mfma_f32_16x16x32_bf16((a),(b),(c),0,0,0)

__device__ __forceinline__ u16 f2bf(float f){
  u32 u = __builtin_bit_cast(u32, f);
  u32 r = u + 0x7FFFu + ((u >> 16) & 1u);
  return (u16)(r >> 16);
}

__device__ __forceinline__ u32 pk_bf16(float lo, float hi){
  u32 w;
  asm("v_cvt_pk_bf16_f32 %0, %1, %2" : "=v"(w) : "v"(lo), "v"(hi));
  return w;
}

__device__ __forceinline__ void gload16(const void* g, void* l){
  __builtin_amdgcn_global_load_lds((__attribute__((address_space(1))) void*)(uintptr_t)g,
                                   (__attribute__((address_space(3))) void*)l, 16, 0, 0);
}

// ---------------- fused prep: cast to bf16 | pos_bias | mask pack ----------------
__global__ __launch_bounds__(256) void k_prep(const float* __restrict__ x,
    const float* __restrict__ wq, const float* __restrict__ wk,
    const float* __restrict__ wv, const float* __restrict__ wo,
    const float* __restrict__ pos, const float* __restrict__ wpos,
    const int* __restrict__ mask,
    u16* __restrict__ xb, u16* __restrict__ wqb, u16* __restrict__ wkb,
    u16* __restrict__ wvb, u16* __restrict__ wob,
    float* __restrict__ posb, u64* __restrict__ pm){
  const int bx = blockIdx.x;
  if (bx < 2048){
    for (int j = bx*256 + threadIdx.x; j < 2097152; j += 2048*256){
      const float* src; u16* dst; int off;
      if (j < 1048576){ src = x; dst = xb; off = j; }
      else {
        int r = (j - 1048576) >> 18; off = (j - 1048576) & 262143;
        src = (r==0)?wq:(r==1)?wk:(r==2)?wv:wo;
        dst = (r==0)?wqb:(r==1)?wkb:(r==2)?wvb:wob;
      }
      float4 v = ((const float4*)src)[off];
      ushort4 o;
      o.x = f2bf(v.x); o.y = f2bf(v.y); o.z = f2bf(v.z); o.w = f2bf(v.w);
      ((ushort4*)dst)[off] = o;
    }
  } else if (bx < 3072){
    int row = (bx - 2048)*4 + (threadIdx.x >> 6);
    int lane = threadIdx.x & 63;
    const float* pr = pos + (size_t)row*1024;
    float pv[16];
    #pragma unroll
    for (int t=0;t<4;t++){
      float4 v = ((const float4*)pr)[lane + 64*t];
      pv[4*t+0]=v.x; pv[4*t+1]=v.y; pv[4*t+2]=v.z; pv[4*t+3]=v.w;
    }
    int b = row >> 11, s = row & 2047;
    for (int h=0; h<16; h++){
      const float* wr = wpos + h*1024;
      float acc = 0.f;
      #pragma unroll
      for (int t=0;t<4;t++){
        float4 w = ((const float4*)wr)[lane + 64*t];
        acc += pv[4*t+0]*w.x + pv[4*t+1]*w.y + pv[4*t+2]*w.z + pv[4*t+3]*w.w;
      }
      #pragma unroll
      for (int m=1;m<64;m<<=1) acc += __shfl_xor(acc, m);
      if (lane == 0) posb[(b*16 + h)*2048 + s] = acc * 1.44269504f;
    }
  } else {
    int lb = bx - 3072;
    int wi = (lb*256 + threadIdx.x) >> 6;
    int lane = threadIdx.x & 63;
    for (int w = wi; w < 131072; w += (1024*256)>>6){
      int v = mask[(size_t)w*64 + lane];
      u64 bits = __ballot(v != 0);
      if (lane == 0) pm[w] = bits;
    }
  }
}

// ---------------- fused QKV projection GEMM (dbuf, 1 barrier/tile) ----------------
__global__ __launch_bounds__(256) void k_qkv(const u16* __restrict__ xb,
    const u16* __restrict__ wqb, const u16* __restrict__ wkb, const u16* __restrict__ wvb,
    const float* __restrict__ bq, const float* __restrict__ bk, const float* __restrict__ bv,
    u16* __restrict__ Q, u16* __restrict__ K, u16* __restrict__ V){
  __shared__ __align__(16) u16 As[2][128*32];
  __shared__ __align__(16) u16 Bs[2][128*32];
  const int bx = blockIdx.x, by = blockIdx.y;
  const int tid = threadIdx.x, wid = tid >> 6, lane = tid & 63;
  const int wsel = by >> 3;
  const u16* W = (wsel==0) ? wqb : (wsel==1 ? wkb : wvb);
  const float* bias = (wsel==0) ? bq : (wsel==1 ? bk : bv);
  u16* dst = (wsel==0) ? Q : (wsel==1 ? K : V);
  const int m0 = bx*128, n0 = (by & 7)*128;
  const int wm = wid >> 1, wn = wid & 1;
  const int g8 = (lane >> 4)*8;

  auto stage = [&](int kt, int buf){
    #pragma unroll
    for (int jj=0;jj<2;jj++){
      int sp = wid*2 + jj;
      int p = sp*64 + lane;
      int row = p >> 2, c4 = p & 3;
      gload16(xb + (size_t)(m0+row)*1024 + kt*32 + c4*8, &As[buf][sp*512]);
      gload16(W  + (size_t)(n0+row)*1024 + kt*32 + c4*8, &Bs[buf][sp*512]);
    }
  };

  f32x4 acc[4][4];
  f32x4 z4 = {0.f,0.f,0.f,0.f};
  #pragma unroll
  for (int mf=0;mf<4;mf++)
    #pragma unroll
    for (int nf=0;nf<4;nf++) acc[mf][nf] = z4;

  stage(0, 0);
  __syncthreads();
  for (int kt=0; kt<32; kt++){
    int cur = kt & 1;
    if (kt+1 < 32) stage(kt+1, cur^1);
    short8 a[4], b[4];
    #pragma unroll
    for (int mf=0;mf<4;mf++) a[mf] = *(const short8*)&As[cur][(wm*64 + mf*16 + (lane&15))*32 + g8];
    #pragma unroll
    for (int nf=0;nf<4;nf++) b[nf] = *(const short8*)&Bs[cur][(wn*64 + nf*16 + (lane&15))*32 + g8];
    #pragma unroll
    for (int mf=0;mf<4;mf++)
      #pragma unroll
      for (int nf=0;nf<4;nf++) acc[mf][nf] = MFMA16(a[mf], b[nf], acc[mf][nf]);
    __syncthreads();
  }

  #pragma unroll
  for (int nf=0;nf<4;nf++){
    int nloc = n0 + wn*64 + nf*16 + (lane & 15);
    float bb = bias[nloc];
    int h = nloc >> 6, d = nloc & 63;
    #pragma unroll
    for (int mf=0;mf<4;mf++)
      #pragma unroll
      for (int i=0;i<4;i++){
        int m = m0 + wm*64 + mf*16 + (lane>>4)*4 + i;
        int bt = m >> 11, s = m & 2047;
        u16 val = f2bf(acc[mf][nf][i] + bb);
        if (wsel == 2)
          dst[((size_t)((bt*16 + h)*64 + d))*2048 + s] = val;      // V^T: (b,h,d,s)
        else
          dst[((size_t)((bt*16 + h)*2048 + s))*64 + d] = val;      // (b,h,s,d)
      }
  }
}

// ---------------- flash attention: 128 queries/block (32/wave), KV tile 64 ----------------
// Ks rows PERMUTED: row r holds key tau(r) = 2*(r&15) + ((r>>4)&1) + (r&32).
// => lane c's 4 scores per m-frag are keys {2c,2c+1,2c+32,2c+33}: packable pairs,
//    and packed P lands in NATURAL key order, so PV side is standard.
__global__ __launch_bounds__(256) void k_attn(const u16* __restrict__ Qg, const u16* __restrict__ Kg,
    const u16* __restrict__ Vtg, const float* __restrict__ posb, const u64* __restrict__ pmask,
    u16* __restrict__ AO){
  __shared__ __align__(16) u16 Ks[2][64*64];
  __shared__ __align__(16) u16 Vts[2][64*64];
  __shared__ __align__(16) u16 Ps[4][32*64];
  const int bid0 = blockIdx.x;
  const int bid = (bid0 & 7)*64 + (bid0 >> 3);   // bijective XCD swizzle (512 = 8*64)
  const int bh = bid >> 4;       // 4 bh per XCD -> K/V L2-resident
  const int qt = bid & 15;
  const int b_ = bh >> 4;
  const int h_ = bh & 15;
  const int tid = threadIdx.x, wid = tid >> 6, lane = tid & 63;
  const int g = lane >> 4, c = lane & 15;
  const int q0w = qt*128 + wid*32;
  const float SC = 0.125f * 1.44269504f;   // 1/sqrt(64) * log2(e)

  short8 qf[2][2];
  #pragma unroll
  for (int mf=0;mf<2;mf++){
    const u16* qp = Qg + ((size_t)(bh*2048 + q0w + mf*16 + c))*64 + g*8;
    qf[mf][0] = *(const short8*)qp;
    qf[mf][1] = *(const short8*)(qp + 32);
  }
  f32x4 Oa[2][4];
  f32x4 z4 = {0.f,0.f,0.f,0.f};
  #pragma unroll
  for (int mf=0;mf<2;mf++)
    #pragma unroll
    for (int db=0;db<4;db++) Oa[mf][db] = z4;
  float mi[2][4], li[2][4];
  #pragma unroll
  for (int mf=0;mf<2;mf++)
    #pragma unroll
    for (int i=0;i<4;i++){ mi[mf][i] = -1e30f; li[mf][i] = 0.f; }

  u16* Pw = Ps[wid];

  auto stage = [&](int kt, int buf){
    if (wid < 2){
      #pragma unroll
      for (int jj=0;jj<4;jj++){
        int sx = wid*4 + jj;
        int p = sx*64 + lane;
        int r = p >> 3, o16 = p & 7;
        int tau = 2*(r&15) + ((r>>4)&1) + (r&32);
        gload16(Kg + ((size_t)(bh*2048 + kt*64 + tau))*64 + (o16 ^ (r&7))*8, &Ks[buf][sx*512]);
      }
    } else {
      #pragma unroll
      for (int jj=0;jj<4;jj++){
        int sv = (wid-2)*4 + jj;
        int p = sv*64 + lane;
        int d = p >> 3, o16 = p & 7;
        gload16(Vtg + ((size_t)(bh*64 + d))*2048 + kt*64 + (o16 ^ (d&7))*8, &Vts[buf][sv*512]);
      }
    }
  };

  stage(0, 0);
  __syncthreads();

  for (int kt=0; kt<32; kt++){
    const int cur = kt & 1;
    if (kt+1 < 32) stage(kt+1, cur^1);

    // ---- QK^T: 32 queries x 64 keys; K-fragments shared across m-frags ----
    f32x4 sc[2][4];
    #pragma unroll
    for (int mf=0;mf<2;mf++)
      #pragma unroll
      for (int nf=0;nf<4;nf++) sc[mf][nf] = z4;
    __builtin_amdgcn_s_setprio(1);
    #pragma unroll
    for (int ks=0;ks<2;ks++){
      short8 kb[4];
      #pragma unroll
      for (int nf=0;nf<4;nf++){
        int r = nf*16 + c;
        unsigned off = (unsigned)(r*128 + ks*64 + g*16) ^ (unsigned)((r&7)<<4);
        kb[nf] = *(const short8*)((const char*)&Ks[cur][0] + off);
      }
      #pragma unroll
      for (int nf=0;nf<4;nf++)
        #pragma unroll
        for (int mf=0;mf<2;mf++)
          sc[mf][nf] = MFMA16(qf[mf][ks], kb[nf], sc[mf][nf]);
    }
    __builtin_amdgcn_s_setprio(0);

    // pos bias for keys 2c,2c+1 and 2c+32,2c+33 (shared across m-frags)
    float2 pb01 = *(const float2*)&posb[bh*2048 + kt*64 + 2*c];
    float2 pb23 = *(const float2*)&posb[bh*2048 + kt*64 + 32 + 2*c];
    u64 mw[2][4];
    #pragma unroll
    for (int mf=0;mf<2;mf++)
      #pragma unroll
      for (int i=0;i<4;i++)
        mw[mf][i] = pmask[((size_t)(b_*2048 + q0w + mf*16 + g*4 + i))*32 + kt];

    // ---- online softmax, log2 domain, defer-max; li per-lane partial ----
    float pv_[2][4][4], lmax[2][4];
    #pragma unroll
    for (int mf=0;mf<2;mf++)
      #pragma unroll
      for (int i=0;i<4;i++){
        pv_[mf][0][i] = sc[mf][0][i]*SC + pb01.x;
        pv_[mf][1][i] = sc[mf][1][i]*SC + pb01.y;
        pv_[mf][2][i] = sc[mf][2][i]*SC + pb23.x;
        pv_[mf][3][i] = sc[mf][3][i]*SC + pb23.y;
        u64 m = mw[mf][i];
        if (m != ~0ull){
          u32 lo = (u32)(m >> (2*c));
          u32 hi = (u32)(m >> (2*c + 32));
          if (!(lo & 1u)) pv_[mf][0][i] = -1e30f;
          if (!(lo & 2u)) pv_[mf][1][i] = -1e30f;
          if (!(hi & 1u)) pv_[mf][2][i] = -1e30f;
          if (!(hi & 2u)) pv_[mf][3][i] = -1e30f;
        }
        lmax[mf][i] = fmaxf(fmaxf(pv_[mf][0][i], pv_[mf][1][i]),
                            fmaxf(pv_[mf][2][i], pv_[mf][3][i]));
      }
    float need = -1e30f;
    #pragma unroll
    for (int mf=0;mf<2;mf++)
      #pragma unroll
      for (int i=0;i<4;i++) need = fmaxf(need, lmax[mf][i] - mi[mf][i]);
    if (__any(need > 8.0f)){
      #pragma unroll
      for (int mf=0;mf<2;mf++)
        #pragma unroll
        for (int i=0;i<4;i++){
          float t = lmax[mf][i];
          t = fmaxf(t, __shfl_xor(t, 1));
          t = fmaxf(t, __shfl_xor(t, 2));
          t = fmaxf(t, __shfl_xor(t, 4));
          t = fmaxf(t, __shfl_xor(t, 8));
          float mn = fmaxf(mi[mf][i], t);
          float al = __builtin_amdgcn_exp2f(mi[mf][i] - mn);
          mi[mf][i] = mn;
          li[mf][i] *= al;
          #pragma unroll
          for (int db=0;db<4;db++) Oa[mf][db][i] *= al;
        }
    }
    #pragma unroll
    for (int mf=0;mf<2;mf++)
      #pragma unroll
      for (int i=0;i<4;i++){
        float rs = 0.f;
        #pragma unroll
        for (int nf=0;nf<4;nf++){
          float e = __builtin_amdgcn_exp2f(pv_[mf][nf][i] - mi[mf][i]);
          pv_[mf][nf][i] = e;
          rs += e;
        }
        li[mf][i] += rs;
      }

    // ---- P -> LDS packed (keys 2c,2c+1 | 2c+32,2c+33), natural key order ----
    #pragma unroll
    for (int mf=0;mf<2;mf++)
      #pragma unroll
      for (int i=0;i<4;i++){
        int qr = mf*16 + g*4 + i;
        u32 w0 = pk_bf16(pv_[mf][0][i], pv_[mf][1][i]);
        u32 w1 = pk_bf16(pv_[mf][2][i], pv_[mf][3][i]);
        unsigned o0 = (unsigned)(qr*128 + 4*c) ^ (unsigned)((qr&7)<<4);
        unsigned o1 = (unsigned)(qr*128 + 64 + 4*c) ^ (unsigned)((qr&7)<<4);
        *(u32*)((char*)Pw + o0) = w0;
        *(u32*)((char*)Pw + o1) = w1;
      }

    // ---- PV: O[q][d] += sum_key P[q][key] * Vt[d][key]; V-frags shared ----
    __builtin_amdgcn_s_setprio(1);
    #pragma unroll
    for (int ks=0;ks<2;ks++){
      short8 pa[2];
      #pragma unroll
      for (int mf=0;mf<2;mf++){
        unsigned aoff = (unsigned)((mf*16 + c)*128 + ks*64 + g*16) ^ (unsigned)((c&7)<<4);
        pa[mf] = *(const short8*)((const char*)Pw + aoff);
      }
      #pragma unroll
      for (int db=0;db<4;db++){
        int d = db*16 + c;
        unsigned boff = (unsigned)(d*128 + ks*64 + g*16) ^ (unsigned)((d&7)<<4);
        short8 vb = *(const short8*)((const char*)&Vts[cur][0] + boff);
        #pragma unroll
        for (int mf=0;mf<2;mf++)
          Oa[mf][db] = MFMA16(pa[mf], vb, Oa[mf][db]);
      }
    }
    __builtin_amdgcn_s_setprio(0);
    __syncthreads();   // one barrier/tile: drains prefetch + protects buffers
  }

  // ---- epilogue: reduce li, normalize, write (b,s,h*64+d) bf16 ----
  #pragma unroll
  for (int mf=0;mf<2;mf++)
    #pragma unroll
    for (int i=0;i<4;i++){
      float s = li[mf][i];
      s += __shfl_xor(s, 1);
      s += __shfl_xor(s, 2);
      s += __shfl_xor(s, 4);
      s += __shfl_xor(s, 8);
      float inv = 1.0f / s;
      int q = q0w + mf*16 + g*4 + i;
      size_t base = ((size_t)(b_*2048 + q))*1024 + h_*64;
      #pragma unroll
      for (int db=0;db<4;db++)
        AO[base + db*16 + c] = f2bf(Oa[mf][db][i] * inv);
    }
}

// ---------------- output projection GEMM (dbuf, 1 barrier/tile) ----------------
__global__ __launch_bounds__(256) void k_out(const u16* __restrict__ A, const u16* __restrict__ W,
    const float* __restrict__ bo, float* __restrict__ out){
  __shared__ __align__(16) u16 As[2][128*32];
  __shared__ __align__(16) u16 Bs[2][128*32];
  const int bx = blockIdx.x, by = blockIdx.y;
  const int tid = threadIdx.x, wid = tid >> 6, lane = tid & 63;
  const int m0 = bx*128, n0 = by*128;
  const int wm = wid >> 1, wn = wid & 1;
  const int g8 = (lane >> 4)*8;

  auto stage = [&](int kt, int buf){
    #pragma unroll
    for (int jj=0;jj<2;jj++){
      int sp = wid*2 + jj;
      int p = sp*64 + lane;
      int row = p >> 2, c4 = p & 3;
      gload16(A + (size_t)(m0+row)*1024 + kt*32 + c4*8, &As[buf][sp*512]);
      gload16(W + (size_t)(n0+row)*1024 + kt*32 + c4*8, &Bs[buf][sp*512]);
    }
  };

  f32x4 acc[4][4];
  f32x4 z4 = {0.f,0.f,0.f,0.f};
  #pragma unroll
  for (int mf=0;mf<4;mf++)
    #pragma unroll
    for (int nf=0;nf<4;nf++) acc[mf][nf] = z4;

  stage(0, 0);
  __syncthreads();
  for (int kt=0; kt<32; kt++){
    int cur = kt & 1;
    if (kt+1 < 32) stage(kt+1, cur^1);
    short8 a[4], b[4];
    #pragma unroll
    for (int mf=0;mf<4;mf++) a[mf] = *(const short8*)&As[cur][(wm*64 + mf*16 + (lane&15))*32 + g8];
    #pragma unroll
    for (int nf=0;nf<4;nf++) b[nf] = *(const short8*)&Bs[cur][(wn*64 + nf*16 + (lane&15))*32 + g8];
    #pragma unroll
    for (int mf=0;mf<4;mf++)
      #pragma unroll
      for (int nf=0;nf<4;nf++) acc[mf][nf] = MFMA16(a[mf], b[nf], acc[mf][nf]);
    __syncthreads();
  }

  #pragma unroll
  for (int nf=0;nf<4;nf++){
    int n = n0 + wn*64 + nf*16 + (lane & 15);
    float bb = bo[n];
    #pragma unroll
    for (int mf=0;mf<4;mf++)
      #pragma unroll
      for (int i=0;i<4;i++){
        int m = m0 + wm*64 + mf*16 + (lane>>4)*4 + i;
        out[(size_t)m*1024 + n] = acc[mf][nf][i] + bb;
      }
  }
}

extern "C" void kernel_launch(void* const* d_in, const int* in_sizes, int n_in,
                              void* d_out, int out_size, void* d_ws, size_t ws_size,
                              hipStream_t stream){
  const float* x    = (const float*)d_in[0];
  const float* pos  = (const float*)d_in[1];
  const int*   mask = (const int*)d_in[2];
  const float* wq   = (const float*)d_in[3];
  const float* bq   = (const float*)d_in[4];
  const float* wk   = (const float*)d_in[5];
  const float* bk   = (const float*)d_in[6];
  const float* wv   = (const float*)d_in[7];
  const float* bv   = (const float*)d_in[8];
  const float* wo   = (const float*)d_in[9];
  const float* bo   = (const float*)d_in[10];
  const float* wpos = (const float*)d_in[11];
  float* out = (float*)d_out;

  char* ws = (char*)d_ws;
  u16* xb   = (u16*)(ws);
  u16* wqb  = (u16*)(ws + ((size_t)8  << 20));
  u16* wkb  = (u16*)(ws + ((size_t)10 << 20));
  u16* wvb  = (u16*)(ws + ((size_t)12 << 20));
  u16* wob  = (u16*)(ws + ((size_t)14 << 20));
  u16* Qb   = (u16*)(ws + ((size_t)16 << 20));
  u16* Kb   = (u16*)(ws + ((size_t)24 << 20));
  u16* Vtb  = (u16*)(ws + ((size_t)32 << 20));
  u16* AO   = (u16*)(ws + ((size_t)40 << 20));
  float* posb = (float*)(ws + ((size_t)48 << 20));
  u64* pm   = (u64*)(ws + ((size_t)49 << 20));

  k_prep<<<dim3(4096), dim3(256), 0, stream>>>(x, wq, wk, wv, wo, pos, wpos, mask,
                                               xb, wqb, wkb, wvb, wob, posb, pm);
  k_qkv<<<dim3(32,24), dim3(256), 0, stream>>>(xb, wqb, wkb, wvb, bq, bk, bv, Qb, Kb, Vtb);
  k_attn<<<dim3(512), dim3(256), 0, stream>>>(Qb, Kb, Vtb, posb, pm, AO);
  k_out<<<dim3(32,8), dim3(256), 0, stream>>>(AO, wob, bo, out);
}